// Round 10
// baseline (617.176 us; speedup 1.0000x reference)
//
#include <hip/hip_runtime.h>
#include <hip/hip_bf16.h>
#include <hip/hip_fp16.h>

// GCN 3-layer + edge-MLP head. R23 = R22 with the b64 double-read removed:
//  - p1a also does global deg[dst]++ / qsumI[dst]+=q (800KB L2-resident
//    counters; R16 proved this histogram is cheap -- only its payload
//    scatter was the disaster).
//  - new d2c kernel: per-node shfl scan of deg + binbase -> C, plus the
//    dinv/g0 (=dinv(.)x@W1) epilogue moved out of p2.
//  - p2 is now SCATTER-ONLY: reads b64 once (was twice = 64MB), curs from C,
//    no qsum atomics, x4-unrolled independent chains.
//  - head batches 2 edges/thread (int2 w2b loads, float2 out stores).
//  - p1b/gathers/dense3 = R22 (331.6us best): one-tile-per-block tile-sort
//    (4 blocks/CU), 8-lane/node full-row gathers, shfl scans.
// Lessons: R15 5B output split fragments write-combining; R16 global atomic
// PAYLOAD scatter is 94B/edge (counters are fine); R18 4-lane gathers lose
// TLP; R19 NT loads break L2 reuse on re-read streams.
// R10 lesson: LDS-atomic bin gather is 2.6x worse than register accumulation.

#define NB1 1024
#define NPB 256
#define MAXBINS 1024
#define LBINS 784
#define TILE 3907
#define QS 16384.0f
#define QINV (1.0f / 16384.0f)

typedef _Float16 h2 __attribute__((ext_vector_type(2)));
typedef _Float16 h4 __attribute__((ext_vector_type(4)));
typedef _Float16 h8 __attribute__((ext_vector_type(8)));

__device__ __forceinline__ float sigmoidf_(float x) {
    return 1.0f / (1.0f + __expf(-x));
}

// ---- zero: clear deg+qsumI
__global__ void zero_kernel(int* __restrict__ p, int nwords) {
    int i = blockIdx.x * 256 + threadIdx.x;
    if (i < nwords) p[i] = 0;
}

// ---- P1a: per-(bin,block) LDS histogram + global deg/qsum histograms
__global__ void p1a_hist(const int* __restrict__ dst, const float* __restrict__ ew,
                         int* __restrict__ bh, int* __restrict__ deg,
                         int* __restrict__ qsumI, int ne, int nbins, int chunk) {
    __shared__ int h[MAXBINS];
    for (int k = threadIdx.x; k < nbins; k += 256) h[k] = 0;
    __syncthreads();
    int base = blockIdx.x * chunk;
    int end = min(base + chunk, ne);
    int e = base + threadIdx.x;
    for (; e + 256 < end; e += 512) {
        int d0 = dst[e];
        int d1 = dst[e + 256];
        int q0 = (int)fminf(sigmoidf_(ew[e]) * QS + 0.5f, 16383.0f);
        int q1 = (int)fminf(sigmoidf_(ew[e + 256]) * QS + 0.5f, 16383.0f);
        atomicAdd(&h[d0 >> 8], 1);
        atomicAdd(&h[d1 >> 8], 1);
        atomicAdd(&deg[d0], 1);
        atomicAdd(&deg[d1], 1);
        atomicAdd(&qsumI[d0], q0);
        atomicAdd(&qsumI[d1], q1);
    }
    if (e < end) {
        int d0 = dst[e];
        int q0 = (int)fminf(sigmoidf_(ew[e]) * QS + 0.5f, 16383.0f);
        atomicAdd(&h[d0 >> 8], 1);
        atomicAdd(&deg[d0], 1);
        atomicAdd(&qsumI[d0], q0);
    }
    __syncthreads();
    for (int k = threadIdx.x; k < nbins; k += 256)
        bh[(size_t)k * NB1 + blockIdx.x] = h[k];
}

// ---- S1: per-bin exclusive scan over NB1 block counts + bin totals
__global__ void s1_scan(int* __restrict__ bh, int* __restrict__ bintot) {
    __shared__ int sums[256];
    constexpr int W = NB1 / 256;
    int* row = bh + (size_t)blockIdx.x * NB1;
    int v[W];
    int s = 0;
#pragma unroll
    for (int j = 0; j < W; ++j) { v[j] = row[threadIdx.x * W + j]; s += v[j]; }
    sums[threadIdx.x] = s;
    __syncthreads();
    for (int o = 1; o < 256; o <<= 1) {
        int t = (threadIdx.x >= o) ? sums[threadIdx.x - o] : 0;
        __syncthreads();
        sums[threadIdx.x] += t;
        __syncthreads();
    }
    int excl = sums[threadIdx.x] - s;
#pragma unroll
    for (int j = 0; j < W; ++j) { row[threadIdx.x * W + j] = excl; excl += v[j]; }
    if (threadIdx.x == 255) bintot[blockIdx.x] = sums[255];
}

// ---- S2: exclusive scan of bin totals -> binbase
__global__ void s2_scan(const int* __restrict__ bintot, int* __restrict__ binbase,
                        int nbins, int ne) {
    __shared__ int tmp[1024];
    int tid = threadIdx.x;
    int v = (tid < nbins) ? bintot[tid] : 0;
    tmp[tid] = v;
    __syncthreads();
    for (int o = 1; o < 1024; o <<= 1) {
        int t = (tid >= o) ? tmp[tid - o] : 0;
        __syncthreads();
        tmp[tid] += t;
        __syncthreads();
    }
    if (tid < nbins) binbase[tid] = tmp[tid] - v;
    if (tid == 0) binbase[nbins] = ne;
}

// ---- D2c: per-node scan (deg) -> C; dinv + fused g0 = dinv (.) (x@W1) fp16
__global__ void d2c_offsets(const int* __restrict__ deg, const int* __restrict__ qsumI,
                            const int* __restrict__ binbase, int* __restrict__ C,
                            float* __restrict__ dinv, const float* __restrict__ x,
                            const float* __restrict__ W1, _Float16* __restrict__ g0,
                            int n, int ne) {
    __shared__ float Ws[56];
    __shared__ int wsum[4];
    int tid = threadIdx.x, lane = tid & 63, wid = tid >> 6;
    if (tid < 56) Ws[tid] = W1[tid];
    int b = blockIdx.x;
    int node = b * NPB + tid;
    int v = (node < n) ? deg[node] : 0;
    int s = v;
    for (int o = 1; o < 64; o <<= 1) {
        int t = __shfl_up(s, o, 64);
        if (lane >= o) s += t;
    }
    if (lane == 63) wsum[wid] = s;
    __syncthreads();
    int wpre = 0;
    for (int w = 0; w < wid; ++w) wpre += wsum[w];
    int excl = binbase[b] + wpre + s - v;
    if (node < n) C[node] = excl;
    if (b == 0 && tid == 0) C[n] = ne;
    if (node < n) {
        float dv = rsqrtf((float)qsumI[node] * QINV + 1.0f);
        dinv[node] = dv;
        float xi[7];
#pragma unroll
        for (int k = 0; k < 7; ++k) xi[k] = x[(size_t)node * 7 + k];
        h8 r;
#pragma unroll
        for (int o = 0; o < 8; ++o) {
            float acc = 0.0f;
#pragma unroll
            for (int k = 0; k < 7; ++k) acc = fmaf(xi[k], Ws[k * 8 + o], acc);
            r[o] = (_Float16)(acc * dv);
        }
        *reinterpret_cast<h8*>(g0 + (size_t)node * 8) = r;
    }
}

// ---- P1b: LDS tile-sort + coalesced flush into bin-grouped u64 array.
// ONE tile per block (TILE == chunk), 4 blocks/CU. No private arrays.
__global__ void p1b_scatter(const int* __restrict__ src, const int* __restrict__ dst,
                            const float* __restrict__ ew, const int* __restrict__ bh,
                            const int* __restrict__ binbase,
                            unsigned long long* __restrict__ b64,
                            int ne, int nbins, int chunk) {
    __shared__ unsigned long long stage[TILE];  // 30.5 KB
    __shared__ int hist[LBINS];
    __shared__ int boff[LBINS];
    __shared__ int cur[LBINS];
    __shared__ int wsum[4];
    int tid = threadIdx.x;
    int lane = tid & 63, wid = tid >> 6;
    for (int k = tid; k < nbins; k += 256)
        cur[k] = binbase[k] + bh[(size_t)k * NB1 + blockIdx.x];
    int t0 = blockIdx.x * chunk;
    int cnt = min(TILE, ne - t0);
    for (int k = tid; k < nbins; k += 256) hist[k] = 0;
    __syncthreads();
    // 1. histogram (dst only; x2 unrolled independent atomics)
    {
        int j = tid;
        for (; j + 256 < cnt; j += 512) {
            int d0 = dst[t0 + j];
            int d1 = dst[t0 + j + 256];
            atomicAdd(&hist[d0 >> 8], 1);
            atomicAdd(&hist[d1 >> 8], 1);
        }
        if (j < cnt) atomicAdd(&hist[dst[t0 + j] >> 8], 1);
    }
    __syncthreads();
    // 2. exclusive scan hist -> boff (4 bins/thread, shfl wave scan)
    int w0 = tid * 4;
    int lv[4];
    int ls = 0;
#pragma unroll
    for (int j = 0; j < 4; ++j) {
        lv[j] = (w0 + j < nbins) ? hist[w0 + j] : 0;
        ls += lv[j];
    }
    int s = ls;
    for (int o = 1; o < 64; o <<= 1) {
        int t = __shfl_up(s, o, 64);
        if (lane >= o) s += t;
    }
    if (lane == 63) wsum[wid] = s;
    __syncthreads();
    int wpre = 0;
    for (int w = 0; w < wid; ++w) wpre += wsum[w];
    int excl = wpre + s - ls;
#pragma unroll
    for (int j = 0; j < 4; ++j) {
        if (w0 + j < nbins) { boff[w0 + j] = excl; excl += lv[j]; }
    }
    __syncthreads();
    // 3. scatter into stage: re-read inputs (dst L2-hot), re-encode,
    //    atomic cursor on boff; x2 unrolled independent chains.
    {
        int j = tid;
        for (; j + 256 < cnt; j += 512) {
            int e0 = t0 + j, e1 = t0 + j + 256;
            int d0 = dst[e0], d1 = dst[e1];
            float wq0 = sigmoidf_(ew[e0]);
            float wq1 = sigmoidf_(ew[e1]);
            int q0 = (int)fminf(wq0 * QS + 0.5f, 16383.0f);
            int q1 = (int)fminf(wq1 * QS + 0.5f, 16383.0f);
            unsigned long long v0 =
                (unsigned long long)((unsigned)src[e0] | ((unsigned)q0 << 18))
                | ((unsigned long long)(d0 & 255) << 32)
                | ((unsigned long long)(d0 >> 8) << 40);
            unsigned long long v1 =
                (unsigned long long)((unsigned)src[e1] | ((unsigned)q1 << 18))
                | ((unsigned long long)(d1 & 255) << 32)
                | ((unsigned long long)(d1 >> 8) << 40);
            int p0 = atomicAdd(&boff[d0 >> 8], 1);
            int p1 = atomicAdd(&boff[d1 >> 8], 1);
            stage[p0] = v0;
            stage[p1] = v1;
        }
        if (j < cnt) {
            int e0 = t0 + j;
            int d0 = dst[e0];
            float wq0 = sigmoidf_(ew[e0]);
            int q0 = (int)fminf(wq0 * QS + 0.5f, 16383.0f);
            unsigned long long v0 =
                (unsigned long long)((unsigned)src[e0] | ((unsigned)q0 << 18))
                | ((unsigned long long)(d0 & 255) << 32)
                | ((unsigned long long)(d0 >> 8) << 40);
            stage[atomicAdd(&boff[d0 >> 8], 1)] = v0;
        }
    }
    __syncthreads();
    // 4. coalesced flush (boff[b]-hist[b] = original in-tile base)
    for (int j = tid; j < cnt; j += 256) {
        unsigned long long v = stage[j];
        int b = (int)(v >> 40);
        b64[cur[b] + (j - (boff[b] - hist[b]))] = v;
    }
}

// ---- P2: scatter-only finalize: b64 read ONCE, curs from C, x4 unrolled.
__global__ void p2_scatter(const unsigned long long* __restrict__ b64,
                           const int* __restrict__ binbase, const int* __restrict__ C,
                           unsigned* __restrict__ edata, int n, int ne) {
    __shared__ int curs[NPB];
    int b = blockIdx.x;
    int tid = threadIdx.x;
    int E0 = binbase[b], E1 = binbase[b + 1];
    int node = b * NPB + tid;
    curs[tid] = (node < n) ? C[node] : ne;
    __syncthreads();
    int k = E0 + tid;
    for (; k + 768 < E1; k += 1024) {
        unsigned long long a = b64[k];
        unsigned long long c = b64[k + 256];
        unsigned long long d = b64[k + 512];
        unsigned long long f = b64[k + 768];
        int dla = (int)((a >> 32) & 0xFF);
        int dlc = (int)((c >> 32) & 0xFF);
        int dld = (int)((d >> 32) & 0xFF);
        int dlf = (int)((f >> 32) & 0xFF);
        int pa = atomicAdd(&curs[dla], 1);
        int pc = atomicAdd(&curs[dlc], 1);
        int pd = atomicAdd(&curs[dld], 1);
        int pf = atomicAdd(&curs[dlf], 1);
        edata[pa] = (unsigned)(a & 0xFFFFFFFFu);
        edata[pc] = (unsigned)(c & 0xFFFFFFFFu);
        edata[pd] = (unsigned)(d & 0xFFFFFFFFu);
        edata[pf] = (unsigned)(f & 0xFFFFFFFFu);
    }
    for (; k < E1; k += 256) {
        unsigned long long a = b64[k];
        int dla = (int)((a >> 32) & 0xFF);
        int pa = atomicAdd(&curs[dla], 1);
        edata[pa] = (unsigned)(a & 0xFFFFFFFFu);
    }
}

// ---- gather1: 8 lanes/node, each lane = full 8-feat row, stride-8 edge split.
// reduce-scatter -> lane l8 owns feature l8; per-lane relu/bias/store (2B).
__global__ void gather1_kernel(const _Float16* __restrict__ g, const float* __restrict__ dinv,
                               const int* __restrict__ C, const unsigned* __restrict__ edata,
                               const float* __restrict__ b1, _Float16* __restrict__ out, int n) {
    __shared__ float bs[8];
    if (threadIdx.x < 8) bs[threadIdx.x] = b1[threadIdx.x];
    __syncthreads();
    long long t = (long long)blockIdx.x * blockDim.x + threadIdx.x;
    int i = (int)(t >> 3);
    int l8 = (int)(t & 7);
    if (i >= n) return;
    int beg = C[i], end = C[i + 1];
    float acc[8] = {0.f, 0.f, 0.f, 0.f, 0.f, 0.f, 0.f, 0.f};
    if (l8 == 0) {  // self-loop (weight 1)
        h8 r = *reinterpret_cast<const h8*>(g + (size_t)i * 8);
#pragma unroll
        for (int j = 0; j < 8; ++j) acc[j] = (float)r[j];
    }
    int k = beg + l8;
    for (; k + 8 < end; k += 16) {  // batch-2 (2 independent chains)
        unsigned v0 = edata[k];
        unsigned v1 = edata[k + 8];
        h8 r0 = *reinterpret_cast<const h8*>(g + (size_t)(v0 & 0x3FFFFu) * 8);
        h8 r1 = *reinterpret_cast<const h8*>(g + (size_t)(v1 & 0x3FFFFu) * 8);
        float w0 = (float)(v0 >> 18) * QINV;
        float w1 = (float)(v1 >> 18) * QINV;
#pragma unroll
        for (int j = 0; j < 8; ++j) acc[j] = fmaf((float)r0[j], w0, acc[j]);
#pragma unroll
        for (int j = 0; j < 8; ++j) acc[j] = fmaf((float)r1[j], w1, acc[j]);
    }
    if (k < end) {
        unsigned v = edata[k];
        float w = (float)(v >> 18) * QINV;
        h8 r = *reinterpret_cast<const h8*>(g + (size_t)(v & 0x3FFFFu) * 8);
#pragma unroll
        for (int j = 0; j < 8; ++j) acc[j] = fmaf((float)r[j], w, acc[j]);
    }
    // reduce-scatter 8 -> 1 across the 8 node-lanes (all indices compile-time)
    bool t4 = (l8 & 4) != 0, t2 = (l8 & 2) != 0, t1 = (l8 & 1) != 0;
    float s4[4];
#pragma unroll
    for (int j = 0; j < 4; ++j) {
        float keep = t4 ? acc[4 + j] : acc[j];
        float send = t4 ? acc[j] : acc[4 + j];
        s4[j] = keep + __shfl_xor(send, 4, 64);
    }
    float s2[2];
#pragma unroll
    for (int j = 0; j < 2; ++j) {
        float keep = t2 ? s4[2 + j] : s4[j];
        float send = t2 ? s4[j] : s4[2 + j];
        s2[j] = keep + __shfl_xor(send, 2, 64);
    }
    float keep = t1 ? s2[1] : s2[0];
    float send = t1 ? s2[0] : s2[1];
    float s = keep + __shfl_xor(send, 1, 64);
    // lane l8 owns feature (4*b4 + 2*b2 + b1) == l8
    float dv = dinv[i];
    out[(size_t)i * 8 + l8] = (_Float16)(dv * fmaxf(dv * s + bs[l8], 0.0f));
}

// ---- gather2: same gather; butterfly allreduce -> raw[8] on all lanes;
// fused dense 8->16 split 2 outputs/lane.
__global__ void gather2_kernel(const _Float16* __restrict__ g, const float* __restrict__ dinv,
                               const int* __restrict__ C, const unsigned* __restrict__ edata,
                               const float* __restrict__ W2, const float* __restrict__ b2,
                               _Float16* __restrict__ out, int n) {
    __shared__ float Ws[128];
    __shared__ float bs[16];
    if (threadIdx.x < 128) Ws[threadIdx.x] = W2[threadIdx.x];
    if (threadIdx.x < 16) bs[threadIdx.x] = b2[threadIdx.x];
    __syncthreads();
    long long t = (long long)blockIdx.x * blockDim.x + threadIdx.x;
    int i = (int)(t >> 3);
    int l8 = (int)(t & 7);
    if (i >= n) return;
    int beg = C[i], end = C[i + 1];
    float acc[8] = {0.f, 0.f, 0.f, 0.f, 0.f, 0.f, 0.f, 0.f};
    if (l8 == 0) {
        h8 r = *reinterpret_cast<const h8*>(g + (size_t)i * 8);
#pragma unroll
        for (int j = 0; j < 8; ++j) acc[j] = (float)r[j];
    }
    int k = beg + l8;
    for (; k + 8 < end; k += 16) {
        unsigned v0 = edata[k];
        unsigned v1 = edata[k + 8];
        h8 r0 = *reinterpret_cast<const h8*>(g + (size_t)(v0 & 0x3FFFFu) * 8);
        h8 r1 = *reinterpret_cast<const h8*>(g + (size_t)(v1 & 0x3FFFFu) * 8);
        float w0 = (float)(v0 >> 18) * QINV;
        float w1 = (float)(v1 >> 18) * QINV;
#pragma unroll
        for (int j = 0; j < 8; ++j) acc[j] = fmaf((float)r0[j], w0, acc[j]);
#pragma unroll
        for (int j = 0; j < 8; ++j) acc[j] = fmaf((float)r1[j], w1, acc[j]);
    }
    if (k < end) {
        unsigned v = edata[k];
        float w = (float)(v >> 18) * QINV;
        h8 r = *reinterpret_cast<const h8*>(g + (size_t)(v & 0x3FFFFu) * 8);
#pragma unroll
        for (int j = 0; j < 8; ++j) acc[j] = fmaf((float)r[j], w, acc[j]);
    }
    // butterfly allreduce: all 8 lanes get full raw[8] (needed for dense)
#pragma unroll
    for (int j = 0; j < 8; ++j) {
        acc[j] += __shfl_xor(acc[j], 1, 64);
        acc[j] += __shfl_xor(acc[j], 2, 64);
        acc[j] += __shfl_xor(acc[j], 4, 64);
    }
    float dv = dinv[i];
    float raw[8];
#pragma unroll
    for (int j = 0; j < 8; ++j) raw[j] = acc[j] * dv;
    int o0 = l8 * 2;
    h2 o2;
#pragma unroll
    for (int jo = 0; jo < 2; ++jo) {
        int o = o0 + jo;
        float h = bs[o];
#pragma unroll
        for (int k2 = 0; k2 < 8; ++k2) h = fmaf(raw[k2], Ws[k2 * 16 + o], h);
        o2[jo] = (_Float16)(dv * fmaxf(h, 0.0f));
    }
    *reinterpret_cast<h2*>(out + (size_t)i * 16 + o0) = o2;
}

// ---- gather3: pure gather over 16-feat rows (2x h8). reduce-scatter 16->2,
// lane l8 owns features 2*l8, 2*l8+1; writes raw3 (dinv-normalized agg, fp16).
__global__ void gather3_kernel(const _Float16* __restrict__ g, const float* __restrict__ dinv,
                               const int* __restrict__ C, const unsigned* __restrict__ edata,
                               _Float16* __restrict__ raw3, int n) {
    long long t = (long long)blockIdx.x * blockDim.x + threadIdx.x;
    int i = (int)(t >> 3);
    int l8 = (int)(t & 7);
    if (i >= n) return;
    int beg = C[i], end = C[i + 1];
    float acc[16];
#pragma unroll
    for (int j = 0; j < 16; ++j) acc[j] = 0.0f;
    if (l8 == 0) {
        h8 r0 = *reinterpret_cast<const h8*>(g + (size_t)i * 16);
        h8 r1 = *reinterpret_cast<const h8*>(g + (size_t)i * 16 + 8);
#pragma unroll
        for (int j = 0; j < 8; ++j) { acc[j] = (float)r0[j]; acc[8 + j] = (float)r1[j]; }
    }
    int k = beg + l8;
    for (; k + 8 < end; k += 16) {
        unsigned v0 = edata[k];
        unsigned v1 = edata[k + 8];
        size_t i0 = (size_t)(v0 & 0x3FFFFu) * 16;
        size_t i1 = (size_t)(v1 & 0x3FFFFu) * 16;
        h8 a0 = *reinterpret_cast<const h8*>(g + i0);
        h8 a1 = *reinterpret_cast<const h8*>(g + i0 + 8);
        h8 c0 = *reinterpret_cast<const h8*>(g + i1);
        h8 c1 = *reinterpret_cast<const h8*>(g + i1 + 8);
        float w0 = (float)(v0 >> 18) * QINV;
        float w1 = (float)(v1 >> 18) * QINV;
#pragma unroll
        for (int j = 0; j < 8; ++j) acc[j] = fmaf((float)a0[j], w0, acc[j]);
#pragma unroll
        for (int j = 0; j < 8; ++j) acc[8 + j] = fmaf((float)a1[j], w0, acc[8 + j]);
#pragma unroll
        for (int j = 0; j < 8; ++j) acc[j] = fmaf((float)c0[j], w1, acc[j]);
#pragma unroll
        for (int j = 0; j < 8; ++j) acc[8 + j] = fmaf((float)c1[j], w1, acc[8 + j]);
    }
    if (k < end) {
        unsigned v = edata[k];
        size_t i0 = (size_t)(v & 0x3FFFFu) * 16;
        h8 a0 = *reinterpret_cast<const h8*>(g + i0);
        h8 a1 = *reinterpret_cast<const h8*>(g + i0 + 8);
        float w = (float)(v >> 18) * QINV;
#pragma unroll
        for (int j = 0; j < 8; ++j) acc[j] = fmaf((float)a0[j], w, acc[j]);
#pragma unroll
        for (int j = 0; j < 8; ++j) acc[8 + j] = fmaf((float)a1[j], w, acc[8 + j]);
    }
    // reduce-scatter 16 -> 2
    bool t4 = (l8 & 4) != 0, t2 = (l8 & 2) != 0, t1 = (l8 & 1) != 0;
    float s8[8];
#pragma unroll
    for (int j = 0; j < 8; ++j) {
        float keep = t4 ? acc[8 + j] : acc[j];
        float send = t4 ? acc[j] : acc[8 + j];
        s8[j] = keep + __shfl_xor(send, 4, 64);
    }
    float s4[4];
#pragma unroll
    for (int j = 0; j < 4; ++j) {
        float keep = t2 ? s8[4 + j] : s8[j];
        float send = t2 ? s8[j] : s8[4 + j];
        s4[j] = keep + __shfl_xor(send, 2, 64);
    }
    float s2[2];
#pragma unroll
    for (int j = 0; j < 2; ++j) {
        float keep = t1 ? s4[2 + j] : s4[j];
        float send = t1 ? s4[j] : s4[2 + j];
        s2[j] = keep + __shfl_xor(send, 1, 64);
    }
    // lane l8 owns features (8*b4 + 4*b2 + 2*b1) + j = 2*l8 + j
    float dv = dinv[i];
    h2 o2;
    o2[0] = (_Float16)(s2[0] * dv);
    o2[1] = (_Float16)(s2[1] * dv);
    *reinterpret_cast<h2*>(raw3 + (size_t)i * 16 + l8 * 2) = o2;
}

// ---- dense3: per-node dense 16->32 (relu) + fused head projection -> pqh.
// W3 staged transposed in LDS (WsT[o][k]) so the k-dot reads are float4;
// all lanes read the same LDS address per step -> broadcast, conflict-free.
__global__ void dense3_kernel(const _Float16* __restrict__ raw3,
                              const float* __restrict__ W3, const float* __restrict__ b3,
                              const float* __restrict__ Wl1, const float* __restrict__ bl1,
                              const float* __restrict__ Wl2, const float* __restrict__ bl2,
                              _Float16* __restrict__ pqh, int n) {
    __shared__ __align__(16) float WsT[512];
    __shared__ float bs[32];
    __shared__ float wfs[192];
    __shared__ float bfs[3];
    for (int t = threadIdx.x; t < 512; t += 256) {
        int k = t >> 5, o = t & 31;
        WsT[o * 16 + k] = W3[t];
    }
    if (threadIdx.x < 32) bs[threadIdx.x] = b3[threadIdx.x];
    if (threadIdx.x < 192) {
        int f = threadIdx.x / 3, j = threadIdx.x % 3;
        float a = 0.0f;
#pragma unroll
        for (int k = 0; k < 4; ++k) a = fmaf(Wl1[f * 4 + k], Wl2[k * 3 + j], a);
        wfs[threadIdx.x] = a;
    }
    if (threadIdx.x < 3) {
        float a = bl2[threadIdx.x];
#pragma unroll
        for (int k = 0; k < 4; ++k) a = fmaf(bl1[k], Wl2[k * 3 + threadIdx.x], a);
        bfs[threadIdx.x] = a;
    }
    __syncthreads();
    int i = blockIdx.x * 256 + threadIdx.x;
    if (i >= n) return;
    h8 r0 = *reinterpret_cast<const h8*>(raw3 + (size_t)i * 16);
    h8 r1 = *reinterpret_cast<const h8*>(raw3 + (size_t)i * 16 + 8);
    float raw[16];
#pragma unroll
    for (int j = 0; j < 8; ++j) { raw[j] = (float)r0[j]; raw[8 + j] = (float)r1[j]; }
    float p0 = bfs[0], p1 = bfs[1], p2 = bfs[2];
    float q0 = 0.0f, q1 = 0.0f, q2 = 0.0f;
#pragma unroll
    for (int o = 0; o < 32; ++o) {
        const float4* w4 = reinterpret_cast<const float4*>(WsT + o * 16);
        float4 wa = w4[0], wb = w4[1], wc = w4[2], wd = w4[3];
        float h = bs[o];
        h = fmaf(raw[0], wa.x, h);  h = fmaf(raw[1], wa.y, h);
        h = fmaf(raw[2], wa.z, h);  h = fmaf(raw[3], wa.w, h);
        h = fmaf(raw[4], wb.x, h);  h = fmaf(raw[5], wb.y, h);
        h = fmaf(raw[6], wb.z, h);  h = fmaf(raw[7], wb.w, h);
        h = fmaf(raw[8], wc.x, h);  h = fmaf(raw[9], wc.y, h);
        h = fmaf(raw[10], wc.z, h); h = fmaf(raw[11], wc.w, h);
        h = fmaf(raw[12], wd.x, h); h = fmaf(raw[13], wd.y, h);
        h = fmaf(raw[14], wd.z, h); h = fmaf(raw[15], wd.w, h);
        h = fmaxf(h, 0.0f);
        p0 = fmaf(h, wfs[o * 3 + 0], p0);
        p1 = fmaf(h, wfs[o * 3 + 1], p1);
        p2 = fmaf(h, wfs[o * 3 + 2], p2);
        q0 = fmaf(h, wfs[(32 + o) * 3 + 0], q0);
        q1 = fmaf(h, wfs[(32 + o) * 3 + 1], q1);
        q2 = fmaf(h, wfs[(32 + o) * 3 + 2], q2);
    }
    h8 o8;
    o8[0] = (_Float16)p0; o8[1] = (_Float16)p1; o8[2] = (_Float16)p2; o8[3] = (_Float16)0.0f;
    o8[4] = (_Float16)q0; o8[5] = (_Float16)q1; o8[6] = (_Float16)q2; o8[7] = (_Float16)0.0f;
    *reinterpret_cast<h8*>(pqh + (size_t)i * 8) = o8;
}

// ---- head: out[e] = p[a] + q[b]; 2 edges/thread, int2/float2 vectorized.
__global__ void head_kernel(const int* __restrict__ w2b, const _Float16* __restrict__ pqh,
                            float* __restrict__ out, int nw) {
    int t = blockIdx.x * 256 + threadIdx.x;
    int e0 = t * 2;
    if (e0 >= nw) return;
    if (e0 + 1 < nw) {
        int2 A = *reinterpret_cast<const int2*>(w2b + e0);
        int2 B = *reinterpret_cast<const int2*>(w2b + (size_t)nw + e0);
        h4 P0 = *reinterpret_cast<const h4*>(pqh + (size_t)A.x * 8);
        h4 Q0 = *reinterpret_cast<const h4*>(pqh + (size_t)B.x * 8 + 4);
        h4 P1 = *reinterpret_cast<const h4*>(pqh + (size_t)A.y * 8);
        h4 Q1 = *reinterpret_cast<const h4*>(pqh + (size_t)B.y * 8 + 4);
        float* o = out + (size_t)e0 * 3;
        float2 w01, w23, w45;
        w01.x = (float)P0[0] + (float)Q0[0];
        w01.y = (float)P0[1] + (float)Q0[1];
        w23.x = (float)P0[2] + (float)Q0[2];
        w23.y = (float)P1[0] + (float)Q1[0];
        w45.x = (float)P1[1] + (float)Q1[1];
        w45.y = (float)P1[2] + (float)Q1[2];
        *reinterpret_cast<float2*>(o) = w01;
        *reinterpret_cast<float2*>(o + 2) = w23;
        *reinterpret_cast<float2*>(o + 4) = w45;
    } else {
        int a = w2b[e0];
        int b = w2b[(size_t)nw + e0];
        h4 P = *reinterpret_cast<const h4*>(pqh + (size_t)a * 8);
        h4 Q = *reinterpret_cast<const h4*>(pqh + (size_t)b * 8 + 4);
        out[(size_t)e0 * 3 + 0] = (float)P[0] + (float)Q[0];
        out[(size_t)e0 * 3 + 1] = (float)P[1] + (float)Q[1];
        out[(size_t)e0 * 3 + 2] = (float)P[2] + (float)Q[2];
    }
}

extern "C" void kernel_launch(void* const* d_in, const int* in_sizes, int n_in,
                              void* d_out, int out_size, void* d_ws, size_t ws_size,
                              hipStream_t stream) {
    const float* x   = (const float*)d_in[0];
    const int* eidx  = (const int*)d_in[1];
    const int* w2b   = (const int*)d_in[2];
    const float* ew  = (const float*)d_in[3];
    const float* W1  = (const float*)d_in[4];
    const float* b1  = (const float*)d_in[5];
    const float* W2  = (const float*)d_in[6];
    const float* b2  = (const float*)d_in[7];
    const float* W3  = (const float*)d_in[8];
    const float* b3  = (const float*)d_in[9];
    const float* Wl1 = (const float*)d_in[10];
    const float* bl1 = (const float*)d_in[11];
    const float* Wl2 = (const float*)d_in[12];
    const float* bl2 = (const float*)d_in[13];
    float* out = (float*)d_out;

    const int n  = in_sizes[0] / 7;   // 200000
    const int ne = in_sizes[1] / 2;   // 4000000
    const int nw = in_sizes[2] / 2;   // 2000000
    const int* src = eidx;
    const int* dst = eidx + ne;

    const int nbins = (n + NPB - 1) / NPB;    // 782  (<= LBINS)
    const int chunk = (ne + NB1 - 1) / NB1;   // 3907 (== TILE)

    // ---- workspace layout (4B words) ----
    float*     ws      = (float*)d_ws;
    float*     dinv    = ws;                                    // n
    int*       C       = (int*)(ws + n);                        // n+1 (+pad)
    unsigned*  edata   = (unsigned*)(ws + 2 * (size_t)n + 16);  // ne
    int*       bh      = (int*)(edata + ne);                    // nbins*NB1
    int*       bintot  = bh + (size_t)nbins * NB1;              // MAXBINS
    int*       binbase = bintot + MAXBINS;                      // MAXBINS+1 (+pad)
    int*       deg     = binbase + MAXBINS + 16;                // n
    int*       qsumI   = deg + n;                               // n (contiguous w/ deg)
    _Float16*  g0      = (_Float16*)(qsumI + n);                // n*8 halves (4n words)
    float*     bregion = (float*)(g0 + (size_t)n * 8);          // 2*ne words
    unsigned long long* b64 = (unsigned long long*)bregion;     // ne u64 (dead after p2)
    _Float16*  g1      = (_Float16*)bregion;                    // n*8  halves @ 0   } alias
    _Float16*  g2      = (_Float16*)(bregion + 4 * (size_t)n);  // n*16 halves @ 4n  } into
    _Float16*  pqh     = (_Float16*)(bregion + 12 * (size_t)n); // n*8  halves @ 12n } b64
    _Float16*  raw3    = (_Float16*)(bregion + 16 * (size_t)n); // n*16 halves @ 16n } (24n<2ne)

    const int Bl = 256;
    auto blks = [&](long long t) { return (int)((t + Bl - 1) / Bl); };
    const int nb8 = blks((long long)n * 8);  // 8 lanes per node

    // 1. CSR build (counting sort; tile-sorted write-combined scatter)
    zero_kernel<<<blks(2 * (long long)n), Bl, 0, stream>>>(deg, 2 * n);
    p1a_hist<<<NB1, Bl, 0, stream>>>(dst, ew, bh, deg, qsumI, ne, nbins, chunk);
    s1_scan<<<nbins, Bl, 0, stream>>>(bh, bintot);
    s2_scan<<<1, 1024, 0, stream>>>(bintot, binbase, nbins, ne);
    d2c_offsets<<<nbins, Bl, 0, stream>>>(deg, qsumI, binbase, C, dinv, x, W1, g0, n, ne);
    p1b_scatter<<<NB1, Bl, 0, stream>>>(src, dst, ew, bh, binbase, b64, ne, nbins, chunk);
    p2_scatter<<<nbins, Bl, 0, stream>>>(b64, binbase, C, edata, n, ne);

    // 2. three full-row 8-lane-per-node gather layers (+ split dense3)
    gather1_kernel<<<nb8, Bl, 0, stream>>>(g0, dinv, C, edata, b1, g1, n);
    gather2_kernel<<<nb8, Bl, 0, stream>>>(g1, dinv, C, edata, W2, b2, g2, n);
    gather3_kernel<<<nb8, Bl, 0, stream>>>(g2, dinv, C, edata, raw3, n);
    dense3_kernel<<<blks(n), Bl, 0, stream>>>(raw3, W3, b3, Wl1, bl1, Wl2, bl2, pqh, n);

    // 3. head
    head_kernel<<<blks((nw + 1) / 2), Bl, 0, stream>>>(w2b, pqh, out, nw);
}

// Round 11
// 331.550 us; speedup vs baseline: 1.8615x; 1.8615x over previous
//
#include <hip/hip_runtime.h>
#include <hip/hip_bf16.h>
#include <hip/hip_fp16.h>

// GCN 3-layer + edge-MLP head. R24 = R22 (best measured, 331.6us) + vectorized
// head (2 edges/thread) only.
//  - R23 REVERTED: global atomicAdd deg/qsum histograms cost 305us @ 275MB
//    WRITE (8M random 4B atomics = line-granular fabric RMW). Corrected
//    lesson: R16's d1_degree was never cheap -- it was just hidden below its
//    400us d3 in the top-5. Random global atomics are NEVER cheap here;
//    LDS tile-sort is the only acceptable histogram structure.
//  - R22: one-tile-per-block p1b (TILE==chunk=3907, 4 blocks/CU, LDS 40.7KB),
//    no private arrays (phase 3 re-reads dst/src/ew, L2-hot), shfl scans,
//    atomic-on-boff cursor. p2 reads b64 twice but the 2nd read is L2-hot.
//  - Gathers: 8-lane/node full-row h8 (R18: 4-lane loses TLP), single
//    gather3 (R17: split-pass costs more than L2 saving), x2-unrolled
//    batch loops.
// Lessons: R15 5B output split fragments write-combining; R19 NT loads break
// L2 reuse on re-read streams. R10: LDS-atomic bin gather 2.6x worse than
// register accumulation.

#define NB1 1024
#define NPB 256
#define MAXBINS 1024
#define LBINS 784
#define TILE 3907
#define QS 16384.0f
#define QINV (1.0f / 16384.0f)

typedef _Float16 h2 __attribute__((ext_vector_type(2)));
typedef _Float16 h4 __attribute__((ext_vector_type(4)));
typedef _Float16 h8 __attribute__((ext_vector_type(8)));

__device__ __forceinline__ float sigmoidf_(float x) {
    return 1.0f / (1.0f + __expf(-x));
}

// ---- P1a: per-(bin,block) histogram via LDS
__global__ void p1a_hist(const int* __restrict__ dst, int* __restrict__ bh,
                         int ne, int nbins, int chunk) {
    __shared__ int h[MAXBINS];
    for (int k = threadIdx.x; k < nbins; k += 256) h[k] = 0;
    __syncthreads();
    int base = blockIdx.x * chunk;
    int end = min(base + chunk, ne);
    int e = base + threadIdx.x;
    for (; e + 256 < end; e += 512) {
        int d0 = dst[e];
        int d1 = dst[e + 256];
        atomicAdd(&h[d0 >> 8], 1);
        atomicAdd(&h[d1 >> 8], 1);
    }
    if (e < end) atomicAdd(&h[dst[e] >> 8], 1);
    __syncthreads();
    for (int k = threadIdx.x; k < nbins; k += 256)
        bh[(size_t)k * NB1 + blockIdx.x] = h[k];
}

// ---- S1: per-bin exclusive scan over NB1 block counts + bin totals
__global__ void s1_scan(int* __restrict__ bh, int* __restrict__ bintot) {
    __shared__ int sums[256];
    constexpr int W = NB1 / 256;
    int* row = bh + (size_t)blockIdx.x * NB1;
    int v[W];
    int s = 0;
#pragma unroll
    for (int j = 0; j < W; ++j) { v[j] = row[threadIdx.x * W + j]; s += v[j]; }
    sums[threadIdx.x] = s;
    __syncthreads();
    for (int o = 1; o < 256; o <<= 1) {
        int t = (threadIdx.x >= o) ? sums[threadIdx.x - o] : 0;
        __syncthreads();
        sums[threadIdx.x] += t;
        __syncthreads();
    }
    int excl = sums[threadIdx.x] - s;
#pragma unroll
    for (int j = 0; j < W; ++j) { row[threadIdx.x * W + j] = excl; excl += v[j]; }
    if (threadIdx.x == 255) bintot[blockIdx.x] = sums[255];
}

// ---- S2: exclusive scan of bin totals -> binbase
__global__ void s2_scan(const int* __restrict__ bintot, int* __restrict__ binbase,
                        int nbins, int ne) {
    __shared__ int tmp[1024];
    int tid = threadIdx.x;
    int v = (tid < nbins) ? bintot[tid] : 0;
    tmp[tid] = v;
    __syncthreads();
    for (int o = 1; o < 1024; o <<= 1) {
        int t = (tid >= o) ? tmp[tid - o] : 0;
        __syncthreads();
        tmp[tid] += t;
        __syncthreads();
    }
    if (tid < nbins) binbase[tid] = tmp[tid] - v;
    if (tid == 0) binbase[nbins] = ne;
}

// ---- P1b: LDS tile-sort + coalesced flush into bin-grouped u64 array.
// ONE tile per block (TILE == chunk), 4 blocks/CU. No private arrays.
// shfl scans, atomic-on-boff cursor.
__global__ void p1b_scatter(const int* __restrict__ src, const int* __restrict__ dst,
                            const float* __restrict__ ew, const int* __restrict__ bh,
                            const int* __restrict__ binbase,
                            unsigned long long* __restrict__ b64,
                            int ne, int nbins, int chunk) {
    __shared__ unsigned long long stage[TILE];  // 30.5 KB
    __shared__ int hist[LBINS];                 // 3.1 KB
    __shared__ int boff[LBINS];                 // 3.1 KB
    __shared__ int cur[LBINS];                  // 3.1 KB
    __shared__ int wsum[4];
    int tid = threadIdx.x;
    int lane = tid & 63, wid = tid >> 6;
    for (int k = tid; k < nbins; k += 256)
        cur[k] = binbase[k] + bh[(size_t)k * NB1 + blockIdx.x];
    int t0 = blockIdx.x * chunk;
    int cnt = min(TILE, ne - t0);
    for (int k = tid; k < nbins; k += 256) hist[k] = 0;
    __syncthreads();
    // 1. histogram (dst only; x2 unrolled independent atomics)
    {
        int j = tid;
        for (; j + 256 < cnt; j += 512) {
            int d0 = dst[t0 + j];
            int d1 = dst[t0 + j + 256];
            atomicAdd(&hist[d0 >> 8], 1);
            atomicAdd(&hist[d1 >> 8], 1);
        }
        if (j < cnt) atomicAdd(&hist[dst[t0 + j] >> 8], 1);
    }
    __syncthreads();
    // 2. exclusive scan hist -> boff (4 bins/thread, shfl wave scan)
    int w0 = tid * 4;
    int lv[4];
    int ls = 0;
#pragma unroll
    for (int j = 0; j < 4; ++j) {
        lv[j] = (w0 + j < nbins) ? hist[w0 + j] : 0;
        ls += lv[j];
    }
    int s = ls;
    for (int o = 1; o < 64; o <<= 1) {
        int t = __shfl_up(s, o, 64);
        if (lane >= o) s += t;
    }
    if (lane == 63) wsum[wid] = s;
    __syncthreads();
    int wpre = 0;
    for (int w = 0; w < wid; ++w) wpre += wsum[w];
    int excl = wpre + s - ls;
#pragma unroll
    for (int j = 0; j < 4; ++j) {
        if (w0 + j < nbins) { boff[w0 + j] = excl; excl += lv[j]; }
    }
    __syncthreads();
    // 3. scatter into stage: re-read inputs (dst L2-hot), re-encode,
    //    atomic cursor on boff; x2 unrolled independent chains.
    {
        int j = tid;
        for (; j + 256 < cnt; j += 512) {
            int e0 = t0 + j, e1 = t0 + j + 256;
            int d0 = dst[e0], d1 = dst[e1];
            float wq0 = sigmoidf_(ew[e0]);
            float wq1 = sigmoidf_(ew[e1]);
            int q0 = (int)fminf(wq0 * QS + 0.5f, 16383.0f);
            int q1 = (int)fminf(wq1 * QS + 0.5f, 16383.0f);
            unsigned long long v0 =
                (unsigned long long)((unsigned)src[e0] | ((unsigned)q0 << 18))
                | ((unsigned long long)(d0 & 255) << 32)
                | ((unsigned long long)(d0 >> 8) << 40);
            unsigned long long v1 =
                (unsigned long long)((unsigned)src[e1] | ((unsigned)q1 << 18))
                | ((unsigned long long)(d1 & 255) << 32)
                | ((unsigned long long)(d1 >> 8) << 40);
            int p0 = atomicAdd(&boff[d0 >> 8], 1);
            int p1 = atomicAdd(&boff[d1 >> 8], 1);
            stage[p0] = v0;
            stage[p1] = v1;
        }
        if (j < cnt) {
            int e0 = t0 + j;
            int d0 = dst[e0];
            float wq0 = sigmoidf_(ew[e0]);
            int q0 = (int)fminf(wq0 * QS + 0.5f, 16383.0f);
            unsigned long long v0 =
                (unsigned long long)((unsigned)src[e0] | ((unsigned)q0 << 18))
                | ((unsigned long long)(d0 & 255) << 32)
                | ((unsigned long long)(d0 >> 8) << 40);
            stage[atomicAdd(&boff[d0 >> 8], 1)] = v0;
        }
    }
    __syncthreads();
    // 4. coalesced flush (boff[b]-hist[b] = original in-tile base)
    for (int j = tid; j < cnt; j += 256) {
        unsigned long long v = stage[j];
        int b = (int)(v >> 40);
        b64[cur[b] + (j - (boff[b] - hist[b]))] = v;
    }
}

// ---- P2: per-bin CSR finalize + dinv + fused g0 = dinv (.) (x @ W1) fp16.
// Both b64 passes x2-unrolled (two independent load->LDS-atomic chains/trip).
__global__ void p2_build(const unsigned long long* __restrict__ b64,
                         const int* __restrict__ binbase, unsigned* __restrict__ edata,
                         int* __restrict__ C, float* __restrict__ dinv,
                         const float* __restrict__ x, const float* __restrict__ W1,
                         _Float16* __restrict__ g0, int n, int ne, int nbins) {
    __shared__ int cnt[NPB];
    __shared__ int curs[NPB];
    __shared__ unsigned qsum[NPB];
    __shared__ float Ws[56];
    __shared__ int wsum[4];
    if (threadIdx.x < 56) Ws[threadIdx.x] = W1[threadIdx.x];
    int b = blockIdx.x;
    int E0 = binbase[b], E1 = binbase[b + 1];
    int tid = threadIdx.x;
    int lane = tid & 63, wid = tid >> 6;
    cnt[tid] = 0;
    qsum[tid] = 0;
    __syncthreads();
    {
        int k = E0 + tid;
        for (; k + 256 < E1; k += 512) {
            unsigned long long a = b64[k];
            unsigned long long c = b64[k + 256];
            atomicAdd(&cnt[(int)((a >> 32) & 0xFF)], 1);
            atomicAdd(&cnt[(int)((c >> 32) & 0xFF)], 1);
        }
        if (k < E1)
            atomicAdd(&cnt[(int)((b64[k] >> 32) & 0xFF)], 1);
    }
    __syncthreads();
    int v = cnt[tid];
    int s = v;
    for (int o = 1; o < 64; o <<= 1) {
        int t = __shfl_up(s, o, 64);
        if (lane >= o) s += t;
    }
    if (lane == 63) wsum[wid] = s;
    __syncthreads();
    int wpre = 0;
    for (int w = 0; w < wid; ++w) wpre += wsum[w];
    int excl = wpre + s - v;
    curs[tid] = E0 + excl;
    int node = b * NPB + tid;
    if (node < n) C[node] = E0 + excl;
    if (b == 0 && tid == 0) C[n] = ne;
    __syncthreads();
    {
        int k = E0 + tid;
        for (; k + 256 < E1; k += 512) {
            unsigned long long a = b64[k];
            unsigned long long c = b64[k + 256];
            int dla = (int)((a >> 32) & 0xFF);
            int dlc = (int)((c >> 32) & 0xFF);
            int pa = atomicAdd(&curs[dla], 1);
            int pc = atomicAdd(&curs[dlc], 1);
            edata[pa] = (unsigned)(a & 0xFFFFFFFFu);
            edata[pc] = (unsigned)(c & 0xFFFFFFFFu);
            atomicAdd(&qsum[dla], (unsigned)((a >> 18) & 0x3FFFu));
            atomicAdd(&qsum[dlc], (unsigned)((c >> 18) & 0x3FFFu));
        }
        if (k < E1) {
            unsigned long long a = b64[k];
            int dla = (int)((a >> 32) & 0xFF);
            int pa = atomicAdd(&curs[dla], 1);
            edata[pa] = (unsigned)(a & 0xFFFFFFFFu);
            atomicAdd(&qsum[dla], (unsigned)((a >> 18) & 0x3FFFu));
        }
    }
    __syncthreads();
    if (node < n) {
        float dv = rsqrtf((float)qsum[tid] * QINV + 1.0f);
        dinv[node] = dv;
        float xi[7];
#pragma unroll
        for (int k = 0; k < 7; ++k) xi[k] = x[(size_t)node * 7 + k];
        h8 r;
#pragma unroll
        for (int o = 0; o < 8; ++o) {
            float acc = 0.0f;
#pragma unroll
            for (int k = 0; k < 7; ++k) acc = fmaf(xi[k], Ws[k * 8 + o], acc);
            r[o] = (_Float16)(acc * dv);
        }
        *reinterpret_cast<h8*>(g0 + (size_t)node * 8) = r;
    }
}

// ---- gather1: 8 lanes/node, each lane = full 8-feat row, stride-8 edge split.
// reduce-scatter -> lane l8 owns feature l8; per-lane relu/bias/store (2B).
__global__ void gather1_kernel(const _Float16* __restrict__ g, const float* __restrict__ dinv,
                               const int* __restrict__ C, const unsigned* __restrict__ edata,
                               const float* __restrict__ b1, _Float16* __restrict__ out, int n) {
    __shared__ float bs[8];
    if (threadIdx.x < 8) bs[threadIdx.x] = b1[threadIdx.x];
    __syncthreads();
    long long t = (long long)blockIdx.x * blockDim.x + threadIdx.x;
    int i = (int)(t >> 3);
    int l8 = (int)(t & 7);
    if (i >= n) return;
    int beg = C[i], end = C[i + 1];
    float acc[8] = {0.f, 0.f, 0.f, 0.f, 0.f, 0.f, 0.f, 0.f};
    if (l8 == 0) {  // self-loop (weight 1)
        h8 r = *reinterpret_cast<const h8*>(g + (size_t)i * 8);
#pragma unroll
        for (int j = 0; j < 8; ++j) acc[j] = (float)r[j];
    }
    int k = beg + l8;
    for (; k + 8 < end; k += 16) {  // batch-2 (2 independent chains)
        unsigned v0 = edata[k];
        unsigned v1 = edata[k + 8];
        h8 r0 = *reinterpret_cast<const h8*>(g + (size_t)(v0 & 0x3FFFFu) * 8);
        h8 r1 = *reinterpret_cast<const h8*>(g + (size_t)(v1 & 0x3FFFFu) * 8);
        float w0 = (float)(v0 >> 18) * QINV;
        float w1 = (float)(v1 >> 18) * QINV;
#pragma unroll
        for (int j = 0; j < 8; ++j) acc[j] = fmaf((float)r0[j], w0, acc[j]);
#pragma unroll
        for (int j = 0; j < 8; ++j) acc[j] = fmaf((float)r1[j], w1, acc[j]);
    }
    if (k < end) {
        unsigned v = edata[k];
        float w = (float)(v >> 18) * QINV;
        h8 r = *reinterpret_cast<const h8*>(g + (size_t)(v & 0x3FFFFu) * 8);
#pragma unroll
        for (int j = 0; j < 8; ++j) acc[j] = fmaf((float)r[j], w, acc[j]);
    }
    // reduce-scatter 8 -> 1 across the 8 node-lanes (all indices compile-time)
    bool t4 = (l8 & 4) != 0, t2 = (l8 & 2) != 0, t1 = (l8 & 1) != 0;
    float s4[4];
#pragma unroll
    for (int j = 0; j < 4; ++j) {
        float keep = t4 ? acc[4 + j] : acc[j];
        float send = t4 ? acc[j] : acc[4 + j];
        s4[j] = keep + __shfl_xor(send, 4, 64);
    }
    float s2[2];
#pragma unroll
    for (int j = 0; j < 2; ++j) {
        float keep = t2 ? s4[2 + j] : s4[j];
        float send = t2 ? s4[j] : s4[2 + j];
        s2[j] = keep + __shfl_xor(send, 2, 64);
    }
    float keep = t1 ? s2[1] : s2[0];
    float send = t1 ? s2[0] : s2[1];
    float s = keep + __shfl_xor(send, 1, 64);
    // lane l8 owns feature (4*b4 + 2*b2 + b1) == l8
    float dv = dinv[i];
    out[(size_t)i * 8 + l8] = (_Float16)(dv * fmaxf(dv * s + bs[l8], 0.0f));
}

// ---- gather2: same gather; butterfly allreduce -> raw[8] on all lanes;
// fused dense 8->16 split 2 outputs/lane.
__global__ void gather2_kernel(const _Float16* __restrict__ g, const float* __restrict__ dinv,
                               const int* __restrict__ C, const unsigned* __restrict__ edata,
                               const float* __restrict__ W2, const float* __restrict__ b2,
                               _Float16* __restrict__ out, int n) {
    __shared__ float Ws[128];
    __shared__ float bs[16];
    if (threadIdx.x < 128) Ws[threadIdx.x] = W2[threadIdx.x];
    if (threadIdx.x < 16) bs[threadIdx.x] = b2[threadIdx.x];
    __syncthreads();
    long long t = (long long)blockIdx.x * blockDim.x + threadIdx.x;
    int i = (int)(t >> 3);
    int l8 = (int)(t & 7);
    if (i >= n) return;
    int beg = C[i], end = C[i + 1];
    float acc[8] = {0.f, 0.f, 0.f, 0.f, 0.f, 0.f, 0.f, 0.f};
    if (l8 == 0) {
        h8 r = *reinterpret_cast<const h8*>(g + (size_t)i * 8);
#pragma unroll
        for (int j = 0; j < 8; ++j) acc[j] = (float)r[j];
    }
    int k = beg + l8;
    for (; k + 8 < end; k += 16) {
        unsigned v0 = edata[k];
        unsigned v1 = edata[k + 8];
        h8 r0 = *reinterpret_cast<const h8*>(g + (size_t)(v0 & 0x3FFFFu) * 8);
        h8 r1 = *reinterpret_cast<const h8*>(g + (size_t)(v1 & 0x3FFFFu) * 8);
        float w0 = (float)(v0 >> 18) * QINV;
        float w1 = (float)(v1 >> 18) * QINV;
#pragma unroll
        for (int j = 0; j < 8; ++j) acc[j] = fmaf((float)r0[j], w0, acc[j]);
#pragma unroll
        for (int j = 0; j < 8; ++j) acc[j] = fmaf((float)r1[j], w1, acc[j]);
    }
    if (k < end) {
        unsigned v = edata[k];
        float w = (float)(v >> 18) * QINV;
        h8 r = *reinterpret_cast<const h8*>(g + (size_t)(v & 0x3FFFFu) * 8);
#pragma unroll
        for (int j = 0; j < 8; ++j) acc[j] = fmaf((float)r[j], w, acc[j]);
    }
    // butterfly allreduce: all 8 lanes get full raw[8] (needed for dense)
#pragma unroll
    for (int j = 0; j < 8; ++j) {
        acc[j] += __shfl_xor(acc[j], 1, 64);
        acc[j] += __shfl_xor(acc[j], 2, 64);
        acc[j] += __shfl_xor(acc[j], 4, 64);
    }
    float dv = dinv[i];
    float raw[8];
#pragma unroll
    for (int j = 0; j < 8; ++j) raw[j] = acc[j] * dv;
    int o0 = l8 * 2;
    h2 o2;
#pragma unroll
    for (int jo = 0; jo < 2; ++jo) {
        int o = o0 + jo;
        float h = bs[o];
#pragma unroll
        for (int k2 = 0; k2 < 8; ++k2) h = fmaf(raw[k2], Ws[k2 * 16 + o], h);
        o2[jo] = (_Float16)(dv * fmaxf(h, 0.0f));
    }
    *reinterpret_cast<h2*>(out + (size_t)i * 16 + o0) = o2;
}

// ---- gather3: pure gather over 16-feat rows (2x h8). reduce-scatter 16->2,
// lane l8 owns features 2*l8, 2*l8+1; writes raw3 (dinv-normalized agg, fp16).
__global__ void gather3_kernel(const _Float16* __restrict__ g, const float* __restrict__ dinv,
                               const int* __restrict__ C, const unsigned* __restrict__ edata,
                               _Float16* __restrict__ raw3, int n) {
    long long t = (long long)blockIdx.x * blockDim.x + threadIdx.x;
    int i = (int)(t >> 3);
    int l8 = (int)(t & 7);
    if (i >= n) return;
    int beg = C[i], end = C[i + 1];
    float acc[16];
#pragma unroll
    for (int j = 0; j < 16; ++j) acc[j] = 0.0f;
    if (l8 == 0) {
        h8 r0 = *reinterpret_cast<const h8*>(g + (size_t)i * 16);
        h8 r1 = *reinterpret_cast<const h8*>(g + (size_t)i * 16 + 8);
#pragma unroll
        for (int j = 0; j < 8; ++j) { acc[j] = (float)r0[j]; acc[8 + j] = (float)r1[j]; }
    }
    int k = beg + l8;
    for (; k + 8 < end; k += 16) {
        unsigned v0 = edata[k];
        unsigned v1 = edata[k + 8];
        size_t i0 = (size_t)(v0 & 0x3FFFFu) * 16;
        size_t i1 = (size_t)(v1 & 0x3FFFFu) * 16;
        h8 a0 = *reinterpret_cast<const h8*>(g + i0);
        h8 a1 = *reinterpret_cast<const h8*>(g + i0 + 8);
        h8 c0 = *reinterpret_cast<const h8*>(g + i1);
        h8 c1 = *reinterpret_cast<const h8*>(g + i1 + 8);
        float w0 = (float)(v0 >> 18) * QINV;
        float w1 = (float)(v1 >> 18) * QINV;
#pragma unroll
        for (int j = 0; j < 8; ++j) acc[j] = fmaf((float)a0[j], w0, acc[j]);
#pragma unroll
        for (int j = 0; j < 8; ++j) acc[8 + j] = fmaf((float)a1[j], w0, acc[8 + j]);
#pragma unroll
        for (int j = 0; j < 8; ++j) acc[j] = fmaf((float)c0[j], w1, acc[j]);
#pragma unroll
        for (int j = 0; j < 8; ++j) acc[8 + j] = fmaf((float)c1[j], w1, acc[8 + j]);
    }
    if (k < end) {
        unsigned v = edata[k];
        size_t i0 = (size_t)(v & 0x3FFFFu) * 16;
        h8 a0 = *reinterpret_cast<const h8*>(g + i0);
        h8 a1 = *reinterpret_cast<const h8*>(g + i0 + 8);
        float w = (float)(v >> 18) * QINV;
#pragma unroll
        for (int j = 0; j < 8; ++j) acc[j] = fmaf((float)a0[j], w, acc[j]);
#pragma unroll
        for (int j = 0; j < 8; ++j) acc[8 + j] = fmaf((float)a1[j], w, acc[8 + j]);
    }
    // reduce-scatter 16 -> 2
    bool t4 = (l8 & 4) != 0, t2 = (l8 & 2) != 0, t1 = (l8 & 1) != 0;
    float s8[8];
#pragma unroll
    for (int j = 0; j < 8; ++j) {
        float keep = t4 ? acc[8 + j] : acc[j];
        float send = t4 ? acc[j] : acc[8 + j];
        s8[j] = keep + __shfl_xor(send, 4, 64);
    }
    float s4[4];
#pragma unroll
    for (int j = 0; j < 4; ++j) {
        float keep = t2 ? s8[4 + j] : s8[j];
        float send = t2 ? s8[j] : s8[4 + j];
        s4[j] = keep + __shfl_xor(send, 2, 64);
    }
    float s2[2];
#pragma unroll
    for (int j = 0; j < 2; ++j) {
        float keep = t1 ? s4[2 + j] : s4[j];
        float send = t1 ? s4[j] : s4[2 + j];
        s2[j] = keep + __shfl_xor(send, 1, 64);
    }
    // lane l8 owns features (8*b4 + 4*b2 + 2*b1) + j = 2*l8 + j
    float dv = dinv[i];
    h2 o2;
    o2[0] = (_Float16)(s2[0] * dv);
    o2[1] = (_Float16)(s2[1] * dv);
    *reinterpret_cast<h2*>(raw3 + (size_t)i * 16 + l8 * 2) = o2;
}

// ---- dense3: per-node dense 16->32 (relu) + fused head projection -> pqh.
// W3 staged transposed in LDS (WsT[o][k]) so the k-dot reads are float4;
// all lanes read the same LDS address per step -> broadcast, conflict-free.
__global__ void dense3_kernel(const _Float16* __restrict__ raw3,
                              const float* __restrict__ W3, const float* __restrict__ b3,
                              const float* __restrict__ Wl1, const float* __restrict__ bl1,
                              const float* __restrict__ Wl2, const float* __restrict__ bl2,
                              _Float16* __restrict__ pqh, int n) {
    __shared__ __align__(16) float WsT[512];
    __shared__ float bs[32];
    __shared__ float wfs[192];
    __shared__ float bfs[3];
    for (int t = threadIdx.x; t < 512; t += 256) {
        int k = t >> 5, o = t & 31;
        WsT[o * 16 + k] = W3[t];
    }
    if (threadIdx.x < 32) bs[threadIdx.x] = b3[threadIdx.x];
    if (threadIdx.x < 192) {
        int f = threadIdx.x / 3, j = threadIdx.x % 3;
        float a = 0.0f;
#pragma unroll
        for (int k = 0; k < 4; ++k) a = fmaf(Wl1[f * 4 + k], Wl2[k * 3 + j], a);
        wfs[threadIdx.x] = a;
    }
    if (threadIdx.x < 3) {
        float a = bl2[threadIdx.x];
#pragma unroll
        for (int k = 0; k < 4; ++k) a = fmaf(bl1[k], Wl2[k * 3 + threadIdx.x], a);
        bfs[threadIdx.x] = a;
    }
    __syncthreads();
    int i = blockIdx.x * 256 + threadIdx.x;
    if (i >= n) return;
    h8 r0 = *reinterpret_cast<const h8*>(raw3 + (size_t)i * 16);
    h8 r1 = *reinterpret_cast<const h8*>(raw3 + (size_t)i * 16 + 8);
    float raw[16];
#pragma unroll
    for (int j = 0; j < 8; ++j) { raw[j] = (float)r0[j]; raw[8 + j] = (float)r1[j]; }
    float p0 = bfs[0], p1 = bfs[1], p2 = bfs[2];
    float q0 = 0.0f, q1 = 0.0f, q2 = 0.0f;
#pragma unroll
    for (int o = 0; o < 32; ++o) {
        const float4* w4 = reinterpret_cast<const float4*>(WsT + o * 16);
        float4 wa = w4[0], wb = w4[1], wc = w4[2], wd = w4[3];
        float h = bs[o];
        h = fmaf(raw[0], wa.x, h);  h = fmaf(raw[1], wa.y, h);
        h = fmaf(raw[2], wa.z, h);  h = fmaf(raw[3], wa.w, h);
        h = fmaf(raw[4], wb.x, h);  h = fmaf(raw[5], wb.y, h);
        h = fmaf(raw[6], wb.z, h);  h = fmaf(raw[7], wb.w, h);
        h = fmaf(raw[8], wc.x, h);  h = fmaf(raw[9], wc.y, h);
        h = fmaf(raw[10], wc.z, h); h = fmaf(raw[11], wc.w, h);
        h = fmaf(raw[12], wd.x, h); h = fmaf(raw[13], wd.y, h);
        h = fmaf(raw[14], wd.z, h); h = fmaf(raw[15], wd.w, h);
        h = fmaxf(h, 0.0f);
        p0 = fmaf(h, wfs[o * 3 + 0], p0);
        p1 = fmaf(h, wfs[o * 3 + 1], p1);
        p2 = fmaf(h, wfs[o * 3 + 2], p2);
        q0 = fmaf(h, wfs[(32 + o) * 3 + 0], q0);
        q1 = fmaf(h, wfs[(32 + o) * 3 + 1], q1);
        q2 = fmaf(h, wfs[(32 + o) * 3 + 2], q2);
    }
    h8 o8;
    o8[0] = (_Float16)p0; o8[1] = (_Float16)p1; o8[2] = (_Float16)p2; o8[3] = (_Float16)0.0f;
    o8[4] = (_Float16)q0; o8[5] = (_Float16)q1; o8[6] = (_Float16)q2; o8[7] = (_Float16)0.0f;
    *reinterpret_cast<h8*>(pqh + (size_t)i * 8) = o8;
}

// ---- head: out[e] = p[a] + q[b]; 2 edges/thread, int2/float2 vectorized.
__global__ void head_kernel(const int* __restrict__ w2b, const _Float16* __restrict__ pqh,
                            float* __restrict__ out, int nw) {
    int t = blockIdx.x * 256 + threadIdx.x;
    int e0 = t * 2;
    if (e0 >= nw) return;
    if (e0 + 1 < nw) {
        int2 A = *reinterpret_cast<const int2*>(w2b + e0);
        int2 B = *reinterpret_cast<const int2*>(w2b + (size_t)nw + e0);
        h4 P0 = *reinterpret_cast<const h4*>(pqh + (size_t)A.x * 8);
        h4 Q0 = *reinterpret_cast<const h4*>(pqh + (size_t)B.x * 8 + 4);
        h4 P1 = *reinterpret_cast<const h4*>(pqh + (size_t)A.y * 8);
        h4 Q1 = *reinterpret_cast<const h4*>(pqh + (size_t)B.y * 8 + 4);
        float* o = out + (size_t)e0 * 3;
        float2 w01, w23, w45;
        w01.x = (float)P0[0] + (float)Q0[0];
        w01.y = (float)P0[1] + (float)Q0[1];
        w23.x = (float)P0[2] + (float)Q0[2];
        w23.y = (float)P1[0] + (float)Q1[0];
        w45.x = (float)P1[1] + (float)Q1[1];
        w45.y = (float)P1[2] + (float)Q1[2];
        *reinterpret_cast<float2*>(o) = w01;
        *reinterpret_cast<float2*>(o + 2) = w23;
        *reinterpret_cast<float2*>(o + 4) = w45;
    } else {
        int a = w2b[e0];
        int b = w2b[(size_t)nw + e0];
        h4 P = *reinterpret_cast<const h4*>(pqh + (size_t)a * 8);
        h4 Q = *reinterpret_cast<const h4*>(pqh + (size_t)b * 8 + 4);
        out[(size_t)e0 * 3 + 0] = (float)P[0] + (float)Q[0];
        out[(size_t)e0 * 3 + 1] = (float)P[1] + (float)Q[1];
        out[(size_t)e0 * 3 + 2] = (float)P[2] + (float)Q[2];
    }
}

extern "C" void kernel_launch(void* const* d_in, const int* in_sizes, int n_in,
                              void* d_out, int out_size, void* d_ws, size_t ws_size,
                              hipStream_t stream) {
    const float* x   = (const float*)d_in[0];
    const int* eidx  = (const int*)d_in[1];
    const int* w2b   = (const int*)d_in[2];
    const float* ew  = (const float*)d_in[3];
    const float* W1  = (const float*)d_in[4];
    const float* b1  = (const float*)d_in[5];
    const float* W2  = (const float*)d_in[6];
    const float* b2  = (const float*)d_in[7];
    const float* W3  = (const float*)d_in[8];
    const float* b3  = (const float*)d_in[9];
    const float* Wl1 = (const float*)d_in[10];
    const float* bl1 = (const float*)d_in[11];
    const float* Wl2 = (const float*)d_in[12];
    const float* bl2 = (const float*)d_in[13];
    float* out = (float*)d_out;

    const int n  = in_sizes[0] / 7;   // 200000
    const int ne = in_sizes[1] / 2;   // 4000000
    const int nw = in_sizes[2] / 2;   // 2000000
    const int* src = eidx;
    const int* dst = eidx + ne;

    const int nbins = (n + NPB - 1) / NPB;    // 782  (<= LBINS)
    const int chunk = (ne + NB1 - 1) / NB1;   // 3907 (== TILE)

    // ---- workspace layout (4B words) ----
    float*     ws      = (float*)d_ws;
    float*     dinv    = ws;                                    // n
    int*       C       = (int*)(ws + n);                        // n+1 (+pad)
    unsigned*  edata   = (unsigned*)(ws + 2 * (size_t)n + 16);  // ne
    int*       bh      = (int*)(edata + ne);                    // nbins*NB1
    int*       bintot  = bh + (size_t)nbins * NB1;              // MAXBINS
    int*       binbase = bintot + MAXBINS;                      // MAXBINS+1
    _Float16*  g0      = (_Float16*)(binbase + MAXBINS);        // n*8 halves (2n words)
    float*     bregion = (float*)(g0 + (size_t)n * 8);          // 2*ne words
    unsigned long long* b64 = (unsigned long long*)bregion;     // ne u64 (dead after p2)
    _Float16*  g1      = (_Float16*)bregion;                    // n*8  halves @ 0   } alias
    _Float16*  g2      = (_Float16*)(bregion + 4 * (size_t)n);  // n*16 halves @ 4n  } into
    _Float16*  pqh     = (_Float16*)(bregion + 12 * (size_t)n); // n*8  halves @ 12n } b64
    _Float16*  raw3    = (_Float16*)(bregion + 16 * (size_t)n); // n*16 halves @ 16n } (24n<2ne)

    const int Bl = 256;
    auto blks = [&](long long t) { return (int)((t + Bl - 1) / Bl); };
    const int nb8 = blks((long long)n * 8);  // 8 lanes per node

    // 1. CSR build (counting sort; tile-sorted write-combined scatter)
    p1a_hist<<<NB1, Bl, 0, stream>>>(dst, bh, ne, nbins, chunk);
    s1_scan<<<nbins, Bl, 0, stream>>>(bh, bintot);
    s2_scan<<<1, 1024, 0, stream>>>(bintot, binbase, nbins, ne);
    p1b_scatter<<<NB1, Bl, 0, stream>>>(src, dst, ew, bh, binbase, b64, ne, nbins, chunk);
    p2_build<<<nbins, Bl, 0, stream>>>(b64, binbase, edata, C, dinv, x, W1, g0, n, ne, nbins);

    // 2. three full-row 8-lane-per-node gather layers (+ split dense3)
    gather1_kernel<<<nb8, Bl, 0, stream>>>(g0, dinv, C, edata, b1, g1, n);
    gather2_kernel<<<nb8, Bl, 0, stream>>>(g1, dinv, C, edata, W2, b2, g2, n);
    gather3_kernel<<<nb8, Bl, 0, stream>>>(g2, dinv, C, edata, raw3, n);
    dense3_kernel<<<blks(n), Bl, 0, stream>>>(raw3, W3, b3, Wl1, bl1, Wl2, bl2, pqh, n);

    // 3. head
    head_kernel<<<blks((nw + 1) / 2), Bl, 0, stream>>>(w2b, pqh, out, nw);
}

// Round 12
// 328.331 us; speedup vs baseline: 1.8797x; 1.0098x over previous
//
#include <hip/hip_runtime.h>
#include <hip/hip_bf16.h>
#include <hip/hip_fp16.h>

// GCN 3-layer + edge-MLP head. R25 = R24 with gather3 at 16 lanes/node:
//  - gather3 counters (R24): FETCH 125MB == compulsory 4Mx32B row traffic
//    (zero L2 reuse, 6.4MB table > 4MB/XCD), 3.3TB/s = 50% achievable,
//    VALU 21%, occ 62% -> latency-bound, not BW-bound. R18 measured
//    4-lane < 8-lane (TLP hides latency); extrapolate: 16 lanes/node
//    doubles wave count, 1.25 edges/lane, 1 visit/edge, 4-stage
//    reduce-scatter (xor8/4/2/1), lane l16 owns feature l16.
//  - gather1/2 stay 8-lane (isolate the variable).
//  - rest = R24/R22 (331.6us best): one-tile-per-block p1b tile-sort
//    (4 blocks/CU), p2 double-pass (2nd read L2-hot), vectorized head.
// Lessons: R23 random global atomics 305us/275MB (NEVER cheap, even
// "counters"); R15 5B split fragments write-combining; R16 payload scatter
// 94B/edge; R19 NT loads break L2 reuse. R10: LDS-atomic bin gather 2.6x
// worse than register accumulation.

#define NB1 1024
#define NPB 256
#define MAXBINS 1024
#define LBINS 784
#define TILE 3907
#define QS 16384.0f
#define QINV (1.0f / 16384.0f)

typedef _Float16 h2 __attribute__((ext_vector_type(2)));
typedef _Float16 h4 __attribute__((ext_vector_type(4)));
typedef _Float16 h8 __attribute__((ext_vector_type(8)));

__device__ __forceinline__ float sigmoidf_(float x) {
    return 1.0f / (1.0f + __expf(-x));
}

// ---- P1a: per-(bin,block) histogram via LDS
__global__ void p1a_hist(const int* __restrict__ dst, int* __restrict__ bh,
                         int ne, int nbins, int chunk) {
    __shared__ int h[MAXBINS];
    for (int k = threadIdx.x; k < nbins; k += 256) h[k] = 0;
    __syncthreads();
    int base = blockIdx.x * chunk;
    int end = min(base + chunk, ne);
    int e = base + threadIdx.x;
    for (; e + 256 < end; e += 512) {
        int d0 = dst[e];
        int d1 = dst[e + 256];
        atomicAdd(&h[d0 >> 8], 1);
        atomicAdd(&h[d1 >> 8], 1);
    }
    if (e < end) atomicAdd(&h[dst[e] >> 8], 1);
    __syncthreads();
    for (int k = threadIdx.x; k < nbins; k += 256)
        bh[(size_t)k * NB1 + blockIdx.x] = h[k];
}

// ---- S1: per-bin exclusive scan over NB1 block counts + bin totals
__global__ void s1_scan(int* __restrict__ bh, int* __restrict__ bintot) {
    __shared__ int sums[256];
    constexpr int W = NB1 / 256;
    int* row = bh + (size_t)blockIdx.x * NB1;
    int v[W];
    int s = 0;
#pragma unroll
    for (int j = 0; j < W; ++j) { v[j] = row[threadIdx.x * W + j]; s += v[j]; }
    sums[threadIdx.x] = s;
    __syncthreads();
    for (int o = 1; o < 256; o <<= 1) {
        int t = (threadIdx.x >= o) ? sums[threadIdx.x - o] : 0;
        __syncthreads();
        sums[threadIdx.x] += t;
        __syncthreads();
    }
    int excl = sums[threadIdx.x] - s;
#pragma unroll
    for (int j = 0; j < W; ++j) { row[threadIdx.x * W + j] = excl; excl += v[j]; }
    if (threadIdx.x == 255) bintot[blockIdx.x] = sums[255];
}

// ---- S2: exclusive scan of bin totals -> binbase
__global__ void s2_scan(const int* __restrict__ bintot, int* __restrict__ binbase,
                        int nbins, int ne) {
    __shared__ int tmp[1024];
    int tid = threadIdx.x;
    int v = (tid < nbins) ? bintot[tid] : 0;
    tmp[tid] = v;
    __syncthreads();
    for (int o = 1; o < 1024; o <<= 1) {
        int t = (tid >= o) ? tmp[tid - o] : 0;
        __syncthreads();
        tmp[tid] += t;
        __syncthreads();
    }
    if (tid < nbins) binbase[tid] = tmp[tid] - v;
    if (tid == 0) binbase[nbins] = ne;
}

// ---- P1b: LDS tile-sort + coalesced flush into bin-grouped u64 array.
// ONE tile per block (TILE == chunk), 4 blocks/CU. No private arrays.
// shfl scans, atomic-on-boff cursor.
__global__ void p1b_scatter(const int* __restrict__ src, const int* __restrict__ dst,
                            const float* __restrict__ ew, const int* __restrict__ bh,
                            const int* __restrict__ binbase,
                            unsigned long long* __restrict__ b64,
                            int ne, int nbins, int chunk) {
    __shared__ unsigned long long stage[TILE];  // 30.5 KB
    __shared__ int hist[LBINS];                 // 3.1 KB
    __shared__ int boff[LBINS];                 // 3.1 KB
    __shared__ int cur[LBINS];                  // 3.1 KB
    __shared__ int wsum[4];
    int tid = threadIdx.x;
    int lane = tid & 63, wid = tid >> 6;
    for (int k = tid; k < nbins; k += 256)
        cur[k] = binbase[k] + bh[(size_t)k * NB1 + blockIdx.x];
    int t0 = blockIdx.x * chunk;
    int cnt = min(TILE, ne - t0);
    for (int k = tid; k < nbins; k += 256) hist[k] = 0;
    __syncthreads();
    // 1. histogram (dst only; x2 unrolled independent atomics)
    {
        int j = tid;
        for (; j + 256 < cnt; j += 512) {
            int d0 = dst[t0 + j];
            int d1 = dst[t0 + j + 256];
            atomicAdd(&hist[d0 >> 8], 1);
            atomicAdd(&hist[d1 >> 8], 1);
        }
        if (j < cnt) atomicAdd(&hist[dst[t0 + j] >> 8], 1);
    }
    __syncthreads();
    // 2. exclusive scan hist -> boff (4 bins/thread, shfl wave scan)
    int w0 = tid * 4;
    int lv[4];
    int ls = 0;
#pragma unroll
    for (int j = 0; j < 4; ++j) {
        lv[j] = (w0 + j < nbins) ? hist[w0 + j] : 0;
        ls += lv[j];
    }
    int s = ls;
    for (int o = 1; o < 64; o <<= 1) {
        int t = __shfl_up(s, o, 64);
        if (lane >= o) s += t;
    }
    if (lane == 63) wsum[wid] = s;
    __syncthreads();
    int wpre = 0;
    for (int w = 0; w < wid; ++w) wpre += wsum[w];
    int excl = wpre + s - ls;
#pragma unroll
    for (int j = 0; j < 4; ++j) {
        if (w0 + j < nbins) { boff[w0 + j] = excl; excl += lv[j]; }
    }
    __syncthreads();
    // 3. scatter into stage: re-read inputs (dst L2-hot), re-encode,
    //    atomic cursor on boff; x2 unrolled independent chains.
    {
        int j = tid;
        for (; j + 256 < cnt; j += 512) {
            int e0 = t0 + j, e1 = t0 + j + 256;
            int d0 = dst[e0], d1 = dst[e1];
            float wq0 = sigmoidf_(ew[e0]);
            float wq1 = sigmoidf_(ew[e1]);
            int q0 = (int)fminf(wq0 * QS + 0.5f, 16383.0f);
            int q1 = (int)fminf(wq1 * QS + 0.5f, 16383.0f);
            unsigned long long v0 =
                (unsigned long long)((unsigned)src[e0] | ((unsigned)q0 << 18))
                | ((unsigned long long)(d0 & 255) << 32)
                | ((unsigned long long)(d0 >> 8) << 40);
            unsigned long long v1 =
                (unsigned long long)((unsigned)src[e1] | ((unsigned)q1 << 18))
                | ((unsigned long long)(d1 & 255) << 32)
                | ((unsigned long long)(d1 >> 8) << 40);
            int p0 = atomicAdd(&boff[d0 >> 8], 1);
            int p1 = atomicAdd(&boff[d1 >> 8], 1);
            stage[p0] = v0;
            stage[p1] = v1;
        }
        if (j < cnt) {
            int e0 = t0 + j;
            int d0 = dst[e0];
            float wq0 = sigmoidf_(ew[e0]);
            int q0 = (int)fminf(wq0 * QS + 0.5f, 16383.0f);
            unsigned long long v0 =
                (unsigned long long)((unsigned)src[e0] | ((unsigned)q0 << 18))
                | ((unsigned long long)(d0 & 255) << 32)
                | ((unsigned long long)(d0 >> 8) << 40);
            stage[atomicAdd(&boff[d0 >> 8], 1)] = v0;
        }
    }
    __syncthreads();
    // 4. coalesced flush (boff[b]-hist[b] = original in-tile base)
    for (int j = tid; j < cnt; j += 256) {
        unsigned long long v = stage[j];
        int b = (int)(v >> 40);
        b64[cur[b] + (j - (boff[b] - hist[b]))] = v;
    }
}

// ---- P2: per-bin CSR finalize + dinv + fused g0 = dinv (.) (x @ W1) fp16.
// Both b64 passes x2-unrolled (two independent load->LDS-atomic chains/trip).
__global__ void p2_build(const unsigned long long* __restrict__ b64,
                         const int* __restrict__ binbase, unsigned* __restrict__ edata,
                         int* __restrict__ C, float* __restrict__ dinv,
                         const float* __restrict__ x, const float* __restrict__ W1,
                         _Float16* __restrict__ g0, int n, int ne, int nbins) {
    __shared__ int cnt[NPB];
    __shared__ int curs[NPB];
    __shared__ unsigned qsum[NPB];
    __shared__ float Ws[56];
    __shared__ int wsum[4];
    if (threadIdx.x < 56) Ws[threadIdx.x] = W1[threadIdx.x];
    int b = blockIdx.x;
    int E0 = binbase[b], E1 = binbase[b + 1];
    int tid = threadIdx.x;
    int lane = tid & 63, wid = tid >> 6;
    cnt[tid] = 0;
    qsum[tid] = 0;
    __syncthreads();
    {
        int k = E0 + tid;
        for (; k + 256 < E1; k += 512) {
            unsigned long long a = b64[k];
            unsigned long long c = b64[k + 256];
            atomicAdd(&cnt[(int)((a >> 32) & 0xFF)], 1);
            atomicAdd(&cnt[(int)((c >> 32) & 0xFF)], 1);
        }
        if (k < E1)
            atomicAdd(&cnt[(int)((b64[k] >> 32) & 0xFF)], 1);
    }
    __syncthreads();
    int v = cnt[tid];
    int s = v;
    for (int o = 1; o < 64; o <<= 1) {
        int t = __shfl_up(s, o, 64);
        if (lane >= o) s += t;
    }
    if (lane == 63) wsum[wid] = s;
    __syncthreads();
    int wpre = 0;
    for (int w = 0; w < wid; ++w) wpre += wsum[w];
    int excl = wpre + s - v;
    curs[tid] = E0 + excl;
    int node = b * NPB + tid;
    if (node < n) C[node] = E0 + excl;
    if (b == 0 && tid == 0) C[n] = ne;
    __syncthreads();
    {
        int k = E0 + tid;
        for (; k + 256 < E1; k += 512) {
            unsigned long long a = b64[k];
            unsigned long long c = b64[k + 256];
            int dla = (int)((a >> 32) & 0xFF);
            int dlc = (int)((c >> 32) & 0xFF);
            int pa = atomicAdd(&curs[dla], 1);
            int pc = atomicAdd(&curs[dlc], 1);
            edata[pa] = (unsigned)(a & 0xFFFFFFFFu);
            edata[pc] = (unsigned)(c & 0xFFFFFFFFu);
            atomicAdd(&qsum[dla], (unsigned)((a >> 18) & 0x3FFFu));
            atomicAdd(&qsum[dlc], (unsigned)((c >> 18) & 0x3FFFu));
        }
        if (k < E1) {
            unsigned long long a = b64[k];
            int dla = (int)((a >> 32) & 0xFF);
            int pa = atomicAdd(&curs[dla], 1);
            edata[pa] = (unsigned)(a & 0xFFFFFFFFu);
            atomicAdd(&qsum[dla], (unsigned)((a >> 18) & 0x3FFFu));
        }
    }
    __syncthreads();
    if (node < n) {
        float dv = rsqrtf((float)qsum[tid] * QINV + 1.0f);
        dinv[node] = dv;
        float xi[7];
#pragma unroll
        for (int k = 0; k < 7; ++k) xi[k] = x[(size_t)node * 7 + k];
        h8 r;
#pragma unroll
        for (int o = 0; o < 8; ++o) {
            float acc = 0.0f;
#pragma unroll
            for (int k = 0; k < 7; ++k) acc = fmaf(xi[k], Ws[k * 8 + o], acc);
            r[o] = (_Float16)(acc * dv);
        }
        *reinterpret_cast<h8*>(g0 + (size_t)node * 8) = r;
    }
}

// ---- gather1: 8 lanes/node, each lane = full 8-feat row, stride-8 edge split.
// reduce-scatter -> lane l8 owns feature l8; per-lane relu/bias/store (2B).
__global__ void gather1_kernel(const _Float16* __restrict__ g, const float* __restrict__ dinv,
                               const int* __restrict__ C, const unsigned* __restrict__ edata,
                               const float* __restrict__ b1, _Float16* __restrict__ out, int n) {
    __shared__ float bs[8];
    if (threadIdx.x < 8) bs[threadIdx.x] = b1[threadIdx.x];
    __syncthreads();
    long long t = (long long)blockIdx.x * blockDim.x + threadIdx.x;
    int i = (int)(t >> 3);
    int l8 = (int)(t & 7);
    if (i >= n) return;
    int beg = C[i], end = C[i + 1];
    float acc[8] = {0.f, 0.f, 0.f, 0.f, 0.f, 0.f, 0.f, 0.f};
    if (l8 == 0) {  // self-loop (weight 1)
        h8 r = *reinterpret_cast<const h8*>(g + (size_t)i * 8);
#pragma unroll
        for (int j = 0; j < 8; ++j) acc[j] = (float)r[j];
    }
    int k = beg + l8;
    for (; k + 8 < end; k += 16) {  // batch-2 (2 independent chains)
        unsigned v0 = edata[k];
        unsigned v1 = edata[k + 8];
        h8 r0 = *reinterpret_cast<const h8*>(g + (size_t)(v0 & 0x3FFFFu) * 8);
        h8 r1 = *reinterpret_cast<const h8*>(g + (size_t)(v1 & 0x3FFFFu) * 8);
        float w0 = (float)(v0 >> 18) * QINV;
        float w1 = (float)(v1 >> 18) * QINV;
#pragma unroll
        for (int j = 0; j < 8; ++j) acc[j] = fmaf((float)r0[j], w0, acc[j]);
#pragma unroll
        for (int j = 0; j < 8; ++j) acc[j] = fmaf((float)r1[j], w1, acc[j]);
    }
    if (k < end) {
        unsigned v = edata[k];
        float w = (float)(v >> 18) * QINV;
        h8 r = *reinterpret_cast<const h8*>(g + (size_t)(v & 0x3FFFFu) * 8);
#pragma unroll
        for (int j = 0; j < 8; ++j) acc[j] = fmaf((float)r[j], w, acc[j]);
    }
    // reduce-scatter 8 -> 1 across the 8 node-lanes (all indices compile-time)
    bool t4 = (l8 & 4) != 0, t2 = (l8 & 2) != 0, t1 = (l8 & 1) != 0;
    float s4[4];
#pragma unroll
    for (int j = 0; j < 4; ++j) {
        float keep = t4 ? acc[4 + j] : acc[j];
        float send = t4 ? acc[j] : acc[4 + j];
        s4[j] = keep + __shfl_xor(send, 4, 64);
    }
    float s2[2];
#pragma unroll
    for (int j = 0; j < 2; ++j) {
        float keep = t2 ? s4[2 + j] : s4[j];
        float send = t2 ? s4[j] : s4[2 + j];
        s2[j] = keep + __shfl_xor(send, 2, 64);
    }
    float keep = t1 ? s2[1] : s2[0];
    float send = t1 ? s2[0] : s2[1];
    float s = keep + __shfl_xor(send, 1, 64);
    // lane l8 owns feature (4*b4 + 2*b2 + b1) == l8
    float dv = dinv[i];
    out[(size_t)i * 8 + l8] = (_Float16)(dv * fmaxf(dv * s + bs[l8], 0.0f));
}

// ---- gather2: same gather; butterfly allreduce -> raw[8] on all lanes;
// fused dense 8->16 split 2 outputs/lane.
__global__ void gather2_kernel(const _Float16* __restrict__ g, const float* __restrict__ dinv,
                               const int* __restrict__ C, const unsigned* __restrict__ edata,
                               const float* __restrict__ W2, const float* __restrict__ b2,
                               _Float16* __restrict__ out, int n) {
    __shared__ float Ws[128];
    __shared__ float bs[16];
    if (threadIdx.x < 128) Ws[threadIdx.x] = W2[threadIdx.x];
    if (threadIdx.x < 16) bs[threadIdx.x] = b2[threadIdx.x];
    __syncthreads();
    long long t = (long long)blockIdx.x * blockDim.x + threadIdx.x;
    int i = (int)(t >> 3);
    int l8 = (int)(t & 7);
    if (i >= n) return;
    int beg = C[i], end = C[i + 1];
    float acc[8] = {0.f, 0.f, 0.f, 0.f, 0.f, 0.f, 0.f, 0.f};
    if (l8 == 0) {
        h8 r = *reinterpret_cast<const h8*>(g + (size_t)i * 8);
#pragma unroll
        for (int j = 0; j < 8; ++j) acc[j] = (float)r[j];
    }
    int k = beg + l8;
    for (; k + 8 < end; k += 16) {
        unsigned v0 = edata[k];
        unsigned v1 = edata[k + 8];
        h8 r0 = *reinterpret_cast<const h8*>(g + (size_t)(v0 & 0x3FFFFu) * 8);
        h8 r1 = *reinterpret_cast<const h8*>(g + (size_t)(v1 & 0x3FFFFu) * 8);
        float w0 = (float)(v0 >> 18) * QINV;
        float w1 = (float)(v1 >> 18) * QINV;
#pragma unroll
        for (int j = 0; j < 8; ++j) acc[j] = fmaf((float)r0[j], w0, acc[j]);
#pragma unroll
        for (int j = 0; j < 8; ++j) acc[j] = fmaf((float)r1[j], w1, acc[j]);
    }
    if (k < end) {
        unsigned v = edata[k];
        float w = (float)(v >> 18) * QINV;
        h8 r = *reinterpret_cast<const h8*>(g + (size_t)(v & 0x3FFFFu) * 8);
#pragma unroll
        for (int j = 0; j < 8; ++j) acc[j] = fmaf((float)r[j], w, acc[j]);
    }
    // butterfly allreduce: all 8 lanes get full raw[8] (needed for dense)
#pragma unroll
    for (int j = 0; j < 8; ++j) {
        acc[j] += __shfl_xor(acc[j], 1, 64);
        acc[j] += __shfl_xor(acc[j], 2, 64);
        acc[j] += __shfl_xor(acc[j], 4, 64);
    }
    float dv = dinv[i];
    float raw[8];
#pragma unroll
    for (int j = 0; j < 8; ++j) raw[j] = acc[j] * dv;
    int o0 = l8 * 2;
    h2 o2;
#pragma unroll
    for (int jo = 0; jo < 2; ++jo) {
        int o = o0 + jo;
        float h = bs[o];
#pragma unroll
        for (int k2 = 0; k2 < 8; ++k2) h = fmaf(raw[k2], Ws[k2 * 16 + o], h);
        o2[jo] = (_Float16)(dv * fmaxf(h, 0.0f));
    }
    *reinterpret_cast<h2*>(out + (size_t)i * 16 + o0) = o2;
}

// ---- gather3: 16 lanes/node, full 16-feat rows (2x h8), stride-16 edge split
// (1.25 edges/lane -> 2x waves vs 8-lane for latency hiding). reduce-scatter
// 16->1 (xor8/4/2/1); lane l16 owns feature l16; writes raw3 fp16.
__global__ void gather3_kernel(const _Float16* __restrict__ g, const float* __restrict__ dinv,
                               const int* __restrict__ C, const unsigned* __restrict__ edata,
                               _Float16* __restrict__ raw3, int n) {
    long long t = (long long)blockIdx.x * blockDim.x + threadIdx.x;
    int i = (int)(t >> 4);
    int l16 = (int)(t & 15);
    if (i >= n) return;
    int beg = C[i], end = C[i + 1];
    float acc[16];
#pragma unroll
    for (int j = 0; j < 16; ++j) acc[j] = 0.0f;
    if (l16 == 0) {
        h8 r0 = *reinterpret_cast<const h8*>(g + (size_t)i * 16);
        h8 r1 = *reinterpret_cast<const h8*>(g + (size_t)i * 16 + 8);
#pragma unroll
        for (int j = 0; j < 8; ++j) { acc[j] = (float)r0[j]; acc[8 + j] = (float)r1[j]; }
    }
    int k = beg + l16;
    for (; k + 16 < end; k += 32) {  // batch-2
        unsigned v0 = edata[k];
        unsigned v1 = edata[k + 16];
        size_t i0 = (size_t)(v0 & 0x3FFFFu) * 16;
        size_t i1 = (size_t)(v1 & 0x3FFFFu) * 16;
        h8 a0 = *reinterpret_cast<const h8*>(g + i0);
        h8 a1 = *reinterpret_cast<const h8*>(g + i0 + 8);
        h8 c0 = *reinterpret_cast<const h8*>(g + i1);
        h8 c1 = *reinterpret_cast<const h8*>(g + i1 + 8);
        float w0 = (float)(v0 >> 18) * QINV;
        float w1 = (float)(v1 >> 18) * QINV;
#pragma unroll
        for (int j = 0; j < 8; ++j) acc[j] = fmaf((float)a0[j], w0, acc[j]);
#pragma unroll
        for (int j = 0; j < 8; ++j) acc[8 + j] = fmaf((float)a1[j], w0, acc[8 + j]);
#pragma unroll
        for (int j = 0; j < 8; ++j) acc[j] = fmaf((float)c0[j], w1, acc[j]);
#pragma unroll
        for (int j = 0; j < 8; ++j) acc[8 + j] = fmaf((float)c1[j], w1, acc[8 + j]);
    }
    if (k < end) {
        unsigned v = edata[k];
        size_t i0 = (size_t)(v & 0x3FFFFu) * 16;
        h8 a0 = *reinterpret_cast<const h8*>(g + i0);
        h8 a1 = *reinterpret_cast<const h8*>(g + i0 + 8);
        float w = (float)(v >> 18) * QINV;
#pragma unroll
        for (int j = 0; j < 8; ++j) acc[j] = fmaf((float)a0[j], w, acc[j]);
#pragma unroll
        for (int j = 0; j < 8; ++j) acc[8 + j] = fmaf((float)a1[j], w, acc[8 + j]);
    }
    // reduce-scatter 16 -> 1 across the 16 node-lanes (compile-time indices)
    bool t8 = (l16 & 8) != 0, t4 = (l16 & 4) != 0, t2 = (l16 & 2) != 0, t1 = (l16 & 1) != 0;
    float s8[8];
#pragma unroll
    for (int j = 0; j < 8; ++j) {
        float keep = t8 ? acc[8 + j] : acc[j];
        float send = t8 ? acc[j] : acc[8 + j];
        s8[j] = keep + __shfl_xor(send, 8, 64);
    }
    float s4[4];
#pragma unroll
    for (int j = 0; j < 4; ++j) {
        float keep = t4 ? s8[4 + j] : s8[j];
        float send = t4 ? s8[j] : s8[4 + j];
        s4[j] = keep + __shfl_xor(send, 4, 64);
    }
    float s2[2];
#pragma unroll
    for (int j = 0; j < 2; ++j) {
        float keep = t2 ? s2[0] * 0.0f + (t2 ? s4[2 + j] : s4[j]) : s4[j];
        // (expanded below to avoid self-reference; see plain form)
        keep = t2 ? s4[2 + j] : s4[j];
        float send = t2 ? s4[j] : s4[2 + j];
        s2[j] = keep + __shfl_xor(send, 2, 64);
    }
    float keep1 = t1 ? s2[1] : s2[0];
    float send1 = t1 ? s2[0] : s2[1];
    float s = keep1 + __shfl_xor(send1, 1, 64);
    // lane l16 owns feature 8*t8 + 4*t4 + 2*t2 + t1 == l16
    raw3[(size_t)i * 16 + l16] = (_Float16)(s * dinv[i]);
}

// ---- dense3: per-node dense 16->32 (relu) + fused head projection -> pqh.
// W3 staged transposed in LDS (WsT[o][k]) so the k-dot reads are float4;
// all lanes read the same LDS address per step -> broadcast, conflict-free.
__global__ void dense3_kernel(const _Float16* __restrict__ raw3,
                              const float* __restrict__ W3, const float* __restrict__ b3,
                              const float* __restrict__ Wl1, const float* __restrict__ bl1,
                              const float* __restrict__ Wl2, const float* __restrict__ bl2,
                              _Float16* __restrict__ pqh, int n) {
    __shared__ __align__(16) float WsT[512];
    __shared__ float bs[32];
    __shared__ float wfs[192];
    __shared__ float bfs[3];
    for (int t = threadIdx.x; t < 512; t += 256) {
        int k = t >> 5, o = t & 31;
        WsT[o * 16 + k] = W3[t];
    }
    if (threadIdx.x < 32) bs[threadIdx.x] = b3[threadIdx.x];
    if (threadIdx.x < 192) {
        int f = threadIdx.x / 3, j = threadIdx.x % 3;
        float a = 0.0f;
#pragma unroll
        for (int k = 0; k < 4; ++k) a = fmaf(Wl1[f * 4 + k], Wl2[k * 3 + j], a);
        wfs[threadIdx.x] = a;
    }
    if (threadIdx.x < 3) {
        float a = bl2[threadIdx.x];
#pragma unroll
        for (int k = 0; k < 4; ++k) a = fmaf(bl1[k], Wl2[k * 3 + threadIdx.x], a);
        bfs[threadIdx.x] = a;
    }
    __syncthreads();
    int i = blockIdx.x * 256 + threadIdx.x;
    if (i >= n) return;
    h8 r0 = *reinterpret_cast<const h8*>(raw3 + (size_t)i * 16);
    h8 r1 = *reinterpret_cast<const h8*>(raw3 + (size_t)i * 16 + 8);
    float raw[16];
#pragma unroll
    for (int j = 0; j < 8; ++j) { raw[j] = (float)r0[j]; raw[8 + j] = (float)r1[j]; }
    float p0 = bfs[0], p1 = bfs[1], p2 = bfs[2];
    float q0 = 0.0f, q1 = 0.0f, q2 = 0.0f;
#pragma unroll
    for (int o = 0; o < 32; ++o) {
        const float4* w4 = reinterpret_cast<const float4*>(WsT + o * 16);
        float4 wa = w4[0], wb = w4[1], wc = w4[2], wd = w4[3];
        float h = bs[o];
        h = fmaf(raw[0], wa.x, h);  h = fmaf(raw[1], wa.y, h);
        h = fmaf(raw[2], wa.z, h);  h = fmaf(raw[3], wa.w, h);
        h = fmaf(raw[4], wb.x, h);  h = fmaf(raw[5], wb.y, h);
        h = fmaf(raw[6], wb.z, h);  h = fmaf(raw[7], wb.w, h);
        h = fmaf(raw[8], wc.x, h);  h = fmaf(raw[9], wc.y, h);
        h = fmaf(raw[10], wc.z, h); h = fmaf(raw[11], wc.w, h);
        h = fmaf(raw[12], wd.x, h); h = fmaf(raw[13], wd.y, h);
        h = fmaf(raw[14], wd.z, h); h = fmaf(raw[15], wd.w, h);
        h = fmaxf(h, 0.0f);
        p0 = fmaf(h, wfs[o * 3 + 0], p0);
        p1 = fmaf(h, wfs[o * 3 + 1], p1);
        p2 = fmaf(h, wfs[o * 3 + 2], p2);
        q0 = fmaf(h, wfs[(32 + o) * 3 + 0], q0);
        q1 = fmaf(h, wfs[(32 + o) * 3 + 1], q1);
        q2 = fmaf(h, wfs[(32 + o) * 3 + 2], q2);
    }
    h8 o8;
    o8[0] = (_Float16)p0; o8[1] = (_Float16)p1; o8[2] = (_Float16)p2; o8[3] = (_Float16)0.0f;
    o8[4] = (_Float16)q0; o8[5] = (_Float16)q1; o8[6] = (_Float16)q2; o8[7] = (_Float16)0.0f;
    *reinterpret_cast<h8*>(pqh + (size_t)i * 8) = o8;
}

// ---- head: out[e] = p[a] + q[b]; 2 edges/thread, int2/float2 vectorized.
__global__ void head_kernel(const int* __restrict__ w2b, const _Float16* __restrict__ pqh,
                            float* __restrict__ out, int nw) {
    int t = blockIdx.x * 256 + threadIdx.x;
    int e0 = t * 2;
    if (e0 >= nw) return;
    if (e0 + 1 < nw) {
        int2 A = *reinterpret_cast<const int2*>(w2b + e0);
        int2 B = *reinterpret_cast<const int2*>(w2b + (size_t)nw + e0);
        h4 P0 = *reinterpret_cast<const h4*>(pqh + (size_t)A.x * 8);
        h4 Q0 = *reinterpret_cast<const h4*>(pqh + (size_t)B.x * 8 + 4);
        h4 P1 = *reinterpret_cast<const h4*>(pqh + (size_t)A.y * 8);
        h4 Q1 = *reinterpret_cast<const h4*>(pqh + (size_t)B.y * 8 + 4);
        float* o = out + (size_t)e0 * 3;
        float2 w01, w23, w45;
        w01.x = (float)P0[0] + (float)Q0[0];
        w01.y = (float)P0[1] + (float)Q0[1];
        w23.x = (float)P0[2] + (float)Q0[2];
        w23.y = (float)P1[0] + (float)Q1[0];
        w45.x = (float)P1[1] + (float)Q1[1];
        w45.y = (float)P1[2] + (float)Q1[2];
        *reinterpret_cast<float2*>(o) = w01;
        *reinterpret_cast<float2*>(o + 2) = w23;
        *reinterpret_cast<float2*>(o + 4) = w45;
    } else {
        int a = w2b[e0];
        int b = w2b[(size_t)nw + e0];
        h4 P = *reinterpret_cast<const h4*>(pqh + (size_t)a * 8);
        h4 Q = *reinterpret_cast<const h4*>(pqh + (size_t)b * 8 + 4);
        out[(size_t)e0 * 3 + 0] = (float)P[0] + (float)Q[0];
        out[(size_t)e0 * 3 + 1] = (float)P[1] + (float)Q[1];
        out[(size_t)e0 * 3 + 2] = (float)P[2] + (float)Q[2];
    }
}

extern "C" void kernel_launch(void* const* d_in, const int* in_sizes, int n_in,
                              void* d_out, int out_size, void* d_ws, size_t ws_size,
                              hipStream_t stream) {
    const float* x   = (const float*)d_in[0];
    const int* eidx  = (const int*)d_in[1];
    const int* w2b   = (const int*)d_in[2];
    const float* ew  = (const float*)d_in[3];
    const float* W1  = (const float*)d_in[4];
    const float* b1  = (const float*)d_in[5];
    const float* W2  = (const float*)d_in[6];
    const float* b2  = (const float*)d_in[7];
    const float* W3  = (const float*)d_in[8];
    const float* b3  = (const float*)d_in[9];
    const float* Wl1 = (const float*)d_in[10];
    const float* bl1 = (const float*)d_in[11];
    const float* Wl2 = (const float*)d_in[12];
    const float* bl2 = (const float*)d_in[13];
    float* out = (float*)d_out;

    const int n  = in_sizes[0] / 7;   // 200000
    const int ne = in_sizes[1] / 2;   // 4000000
    const int nw = in_sizes[2] / 2;   // 2000000
    const int* src = eidx;
    const int* dst = eidx + ne;

    const int nbins = (n + NPB - 1) / NPB;    // 782  (<= LBINS)
    const int chunk = (ne + NB1 - 1) / NB1;   // 3907 (== TILE)

    // ---- workspace layout (4B words) ----
    float*     ws      = (float*)d_ws;
    float*     dinv    = ws;                                    // n
    int*       C       = (int*)(ws + n);                        // n+1 (+pad)
    unsigned*  edata   = (unsigned*)(ws + 2 * (size_t)n + 16);  // ne
    int*       bh      = (int*)(edata + ne);                    // nbins*NB1
    int*       bintot  = bh + (size_t)nbins * NB1;              // MAXBINS
    int*       binbase = bintot + MAXBINS;                      // MAXBINS+1
    _Float16*  g0      = (_Float16*)(binbase + MAXBINS);        // n*8 halves (2n words)
    float*     bregion = (float*)(g0 + (size_t)n * 8);          // 2*ne words
    unsigned long long* b64 = (unsigned long long*)bregion;     // ne u64 (dead after p2)
    _Float16*  g1      = (_Float16*)bregion;                    // n*8  halves @ 0   } alias
    _Float16*  g2      = (_Float16*)(bregion + 4 * (size_t)n);  // n*16 halves @ 4n  } into
    _Float16*  pqh     = (_Float16*)(bregion + 12 * (size_t)n); // n*8  halves @ 12n } b64
    _Float16*  raw3    = (_Float16*)(bregion + 16 * (size_t)n); // n*16 halves @ 16n } (24n<2ne)

    const int Bl = 256;
    auto blks = [&](long long t) { return (int)((t + Bl - 1) / Bl); };
    const int nb8 = blks((long long)n * 8);    // 8 lanes per node
    const int nb16 = blks((long long)n * 16);  // 16 lanes per node (gather3)

    // 1. CSR build (counting sort; tile-sorted write-combined scatter)
    p1a_hist<<<NB1, Bl, 0, stream>>>(dst, bh, ne, nbins, chunk);
    s1_scan<<<nbins, Bl, 0, stream>>>(bh, bintot);
    s2_scan<<<1, 1024, 0, stream>>>(bintot, binbase, nbins, ne);
    p1b_scatter<<<NB1, Bl, 0, stream>>>(src, dst, ew, bh, binbase, b64, ne, nbins, chunk);
    p2_build<<<nbins, Bl, 0, stream>>>(b64, binbase, edata, C, dinv, x, W1, g0, n, ne, nbins);

    // 2. three full-row gather layers (+ split dense3)
    gather1_kernel<<<nb8, Bl, 0, stream>>>(g0, dinv, C, edata, b1, g1, n);
    gather2_kernel<<<nb8, Bl, 0, stream>>>(g1, dinv, C, edata, W2, b2, g2, n);
    gather3_kernel<<<nb16, Bl, 0, stream>>>(g2, dinv, C, edata, raw3, n);
    dense3_kernel<<<blks(n), Bl, 0, stream>>>(raw3, W3, b3, Wl1, bl1, Wl2, bl2, pqh, n);

    // 3. head
    head_kernel<<<blks((nw + 1) / 2), Bl, 0, stream>>>(w2b, pqh, out, nw);
}